// Round 7
// baseline (201.856 us; speedup 1.0000x reference)
//
#include <hip/hip_runtime.h>

#define B_ 2
#define L_ 2048
#define D_ 512
#define H_ 8
#define S_ 2048

typedef __attribute__((ext_vector_type(8))) short short8;
typedef __attribute__((ext_vector_type(8))) unsigned short ushort8;
typedef __attribute__((ext_vector_type(4))) unsigned short ushort4v;
typedef __attribute__((ext_vector_type(4))) float f32x4;
typedef __attribute__((ext_vector_type(16))) float f32x16;
typedef __attribute__((ext_vector_type(4))) float float4v;

__device__ __forceinline__ unsigned short f2bf(float f) {
    unsigned u = __float_as_uint(f);
    u += 0x7FFF + ((u >> 16) & 1);   // RTNE
    return (unsigned short)(u >> 16);
}
__device__ __forceinline__ float bf2f(unsigned short s) {
    return __uint_as_float(((unsigned)s) << 16);
}
// f32 -> OCP e4m3 (RTNE, saturating)
__device__ __forceinline__ unsigned char f2fp8(float f) {
    return (unsigned char)(__builtin_amdgcn_cvt_pk_fp8_f32(f, f, 0, false) & 0xff);
}
// pack 8 f32 -> 8 e4m3 bytes in one i64 (byte j = v[j])
__device__ __forceinline__ long pack8fp8(const float* v) {
    int lo = __builtin_amdgcn_cvt_pk_fp8_f32(v[0], v[1], 0, false);
    lo = __builtin_amdgcn_cvt_pk_fp8_f32(v[2], v[3], lo, true);
    int hi = __builtin_amdgcn_cvt_pk_fp8_f32(v[4], v[5], 0, false);
    hi = __builtin_amdgcn_cvt_pk_fp8_f32(v[6], v[7], hi, true);
    union { int i[2]; long l; } u;
    u.i[0] = lo; u.i[1] = hi;
    return u.l;
}
// swap bits 2 and 3 (self-inverse) — K-row permutation making S^T C-regs = PV B-frag order
__device__ __forceinline__ int swap23(int x) {
    return (x & ~12) | ((x & 4) << 1) | ((x & 8) >> 1);
}
// async global->LDS, 16B per lane; LDS dest = uniform base + lane*16
__device__ __forceinline__ void async16(void* lds, const void* g) {
    __builtin_amdgcn_global_load_lds(
        (const __attribute__((address_space(1))) void*)(g),
        (__attribute__((address_space(3))) void*)(lds), 16, 0, 0);
}

// ---------------- fused: fp32->bf16 converts (blocks 0..3071) + content bias (blocks 3072..4095) ----------------
// cb stored FRAG-MAJOR f32, PRE-SCALED by log2e/8: cbf[((b*8+h)*64+T)*32 + hi*16 + R] so the flash
// softmax reads its 16 values with zero unpack VALU (R static, hi baked into the load address).
__global__ __launch_bounds__(256) void cvt_cb(const float* __restrict__ x,
                                              const float* __restrict__ w0, const float* __restrict__ w1,
                                              const float* __restrict__ w2, const float* __restrict__ w3,
                                              const float* __restrict__ Wb,
                                              unsigned short* __restrict__ xb,
                                              unsigned short* __restrict__ d0, unsigned short* __restrict__ d1,
                                              unsigned short* __restrict__ d2, unsigned short* __restrict__ d3,
                                              float* __restrict__ cbf) {
    if (blockIdx.x < 3072) {
        int i = blockIdx.x * 256 + threadIdx.x;   // [0, 786432)
        const float* s;
        unsigned short* d;
        int idx;
        if (i < 524288) { s = x; d = xb; idx = i; }
        else {
            int off = i - 524288;                  // [0, 262144): 4 weights x 65536 float4
            int wsel = off >> 16; idx = off & 65535;
            s = (wsel == 0) ? w0 : (wsel == 1) ? w1 : (wsel == 2) ? w2 : w3;
            d = (wsel == 0) ? d0 : (wsel == 1) ? d1 : (wsel == 2) ? d2 : d3;
        }
        float4v v = *(const float4v*)(s + (size_t)idx * 4);
        ushort4v o;
        o[0] = f2bf(v[0]); o[1] = f2bf(v[1]); o[2] = f2bf(v[2]); o[3] = f2bf(v[3]);
        *(ushort4v*)(d + (size_t)idx * 4) = o;
    } else {
        const int tid = threadIdx.x, w = tid >> 6, lane = tid & 63;
        const int row = (blockIdx.x - 3072) * 4 + w;   // [0, 4096)
        const int h = lane >> 3, seg = lane & 7;
        const float* xp = x + (size_t)row * 512 + seg * 64;
        const float* wp = Wb + (size_t)h * 512 + seg * 64;
        float acc = 0.f;
        #pragma unroll
        for (int j = 0; j < 16; ++j) {
            float4v xv = *(const float4v*)(xp + j * 4);
            float4v wv = *(const float4v*)(wp + j * 4);
            acc += xv[0] * wv[0] + xv[1] * wv[1] + xv[2] * wv[2] + xv[3] * wv[3];
        }
        acc += __shfl_xor(acc, 1);
        acc += __shfl_xor(acc, 2);
        acc += __shfl_xor(acc, 4);
        if (seg == 0) {
            int b = row >> 11, s = row & 2047;
            // s -> (T, off) -> (R, hi): off = r2 + 8u - 4(u&1) + 8hi (softmax C-layout)
            int T = s >> 5, off = s & 31;
            int r2 = off & 3, k = off >> 2;
            int u = (k & 1) + ((k >> 2) << 1), hi2 = (k >> 1) & 1;
            int R = 4 * u + r2;
            cbf[((size_t)((b * 8 + h) * 64 + T)) * 32 + hi2 * 16 + R] = acc * 0.125f * 1.44269504f;
        }
    }
}

// ---------------- 128x128-tile GEMM core: 4 waves in 2x2, each 64x64 quadrant ----------------
__device__ __forceinline__ void gemm128_core(const unsigned short* __restrict__ Ap,
                                             const unsigned short* __restrict__ Bp,
                                             short* sA, short* sB, int tid, f32x4 c[4][4]) {
    const int w = tid >> 6, lane = tid & 63, quad = lane >> 4, l15 = lane & 15;
    const int wm = (w >> 1) * 64, wn = (w & 1) * 64;
    for (int kc = 0; kc < 8; ++kc) {
        __syncthreads();
        #pragma unroll
        for (int j = 0; j < 4; ++j) {
            int i = tid + j * 256;          // 1024 slots = 128 rows x 64 cols / 8
            int row = i >> 3, seg = i & 7;
            *(ushort8*)&sA[row * 72 + seg * 8] = *(const ushort8*)(Ap + (size_t)row * 512 + kc * 64 + seg * 8);
            *(ushort8*)&sB[row * 72 + seg * 8] = *(const ushort8*)(Bp + (size_t)row * 512 + kc * 64 + seg * 8);
        }
        __syncthreads();
        #pragma unroll
        for (int ks = 0; ks < 2; ++ks) {
            short8 a[4], b[4];
            #pragma unroll
            for (int ii = 0; ii < 4; ++ii)
                a[ii] = *(const short8*)&sA[(wm + ii * 16 + l15) * 72 + ks * 32 + quad * 8];
            #pragma unroll
            for (int jj = 0; jj < 4; ++jj)
                b[jj] = *(const short8*)&sB[(wn + jj * 16 + l15) * 72 + ks * 32 + quad * 8];
            #pragma unroll
            for (int ii = 0; ii < 4; ++ii)
                #pragma unroll
                for (int jj = 0; jj < 4; ++jj)
                    c[ii][jj] = __builtin_amdgcn_mfma_f32_16x16x32_bf16(a[ii], b[jj], c[ii][jj], 0, 0, 0);
        }
    }
}

// ---------------- q,k,v projections (128x128 tiles) ----------------
// q: row-major bf16 (flash folds mixing + quantizes per-head in-register).
// K: fp8 e4m3 (x32, NO mixing) A-frag pair-packed, rows sigma-permuted:
//    byte = ((b*64 + (s>>5))*16 + (d>>5))*1024 + (((d>>3)&1)*32 + swap23(s&31))*16 + ((d>>4)&1)*8 + (d&7)
// V: frag-major vfrag[(b,h,T,f)][lane*8] — flash reads one dwordx4/lane.
__global__ __launch_bounds__(256) void gemm_qkv(const unsigned short* __restrict__ xb,
                                                const unsigned short* __restrict__ Wqb,
                                                const unsigned short* __restrict__ Wkb,
                                                const unsigned short* __restrict__ Wvb,
                                                unsigned short* __restrict__ qb,
                                                unsigned char* __restrict__ kpack8,
                                                unsigned short* __restrict__ vfrag) {
    __shared__ short sA[128 * 72];
    __shared__ short sB[128 * 72];
    const int m0 = blockIdx.x * 128, n0 = blockIdx.y * 128, z = blockIdx.z;
    const unsigned short* Bsel = (z == 0) ? Wqb : ((z == 1) ? Wkb : Wvb);
    f32x4 c[4][4];
    #pragma unroll
    for (int ii = 0; ii < 4; ++ii)
        #pragma unroll
        for (int jj = 0; jj < 4; ++jj) { f32x4 zv = {0.f, 0.f, 0.f, 0.f}; c[ii][jj] = zv; }
    gemm128_core(xb + (size_t)m0 * 512, Bsel + (size_t)n0 * 512, sA, sB, threadIdx.x, c);
    const int tid = threadIdx.x, w = tid >> 6, lane = tid & 63, quad = lane >> 4, l15 = lane & 15;
    const int wm = (w >> 1) * 64, wn = (w & 1) * 64;
    #pragma unroll
    for (int ii = 0; ii < 4; ++ii) {
        const int mb = m0 + wm + ii * 16 + quad * 4;
        const int bb = mb >> 11;
        if (z == 0) {
            #pragma unroll
            for (int jj = 0; jj < 4; ++jj) {
                int ncol = n0 + wn + jj * 16 + l15;
                #pragma unroll
                for (int r = 0; r < 4; ++r)
                    qb[(size_t)(mb + r) * 512 + ncol] = f2bf(c[ii][jj][r]);
            }
        } else if (z == 1) {
            #pragma unroll
            for (int jj = 0; jj < 4; ++jj) {
                int d = n0 + wn + jj * 16 + l15;
                int pair = d >> 5, fh = (d >> 4) & 1, hid = (d >> 3) & 1, jq = d & 7;
                #pragma unroll
                for (int r = 0; r < 4; ++r) {
                    int s = (mb + r) & 2047;
                    int t = s >> 5, rr = swap23(s & 31);
                    kpack8[(((size_t)(bb * 64 + t) * 16 + pair) << 10)
                           + (hid * 32 + rr) * 16 + fh * 8 + jq] = f2fp8(c[ii][jj][r] * 32.f);
                }
            }
        } else {
            const int hh = (n0 + wn) >> 6;
            const int s = mb & 2047;              // s..s+3 along r, s%4==0
            #pragma unroll
            for (int jj = 0; jj < 4; ++jj) {
                int dh = jj * 16 + l15;
                ushort4v o;
                o[0] = f2bf(c[ii][jj][0]); o[1] = f2bf(c[ii][jj][1]);
                o[2] = f2bf(c[ii][jj][2]); o[3] = f2bf(c[ii][jj][3]);
                size_t blk = ((size_t)(bb * H_ + hh) * 64 + (s >> 5)) * 4
                           + ((dh >> 5) * 2 + ((s >> 4) & 1));
                *(ushort4v*)(vfrag + blk * 512 + (dh & 31) * 8 + ((s >> 3) & 1) * 256 + (s & 7)) = o;
            }
        }
    }
}

// ---------------- output projection (128x128 tiles, fp32 out + bias) ----------------
__global__ __launch_bounds__(256) void gemm_out(const unsigned short* __restrict__ ctxb,
                                                const unsigned short* __restrict__ Wdb,
                                                const float* __restrict__ bd,
                                                float* __restrict__ out) {
    __shared__ short sA[128 * 72];
    __shared__ short sB[128 * 72];
    const int m0 = blockIdx.x * 128, n0 = blockIdx.y * 128;
    f32x4 c[4][4];
    #pragma unroll
    for (int ii = 0; ii < 4; ++ii)
        #pragma unroll
        for (int jj = 0; jj < 4; ++jj) { f32x4 zv = {0.f, 0.f, 0.f, 0.f}; c[ii][jj] = zv; }
    gemm128_core(ctxb + (size_t)m0 * 512, Wdb + (size_t)n0 * 512, sA, sB, threadIdx.x, c);
    const int tid = threadIdx.x, w = tid >> 6, lane = tid & 63, quad = lane >> 4, l15 = lane & 15;
    const int wm = (w >> 1) * 64, wn = (w & 1) * 64;
    #pragma unroll
    for (int ii = 0; ii < 4; ++ii) {
        const int mb = m0 + wm + ii * 16 + quad * 4;
        #pragma unroll
        for (int jj = 0; jj < 4; ++jj) {
            int ncol = n0 + wn + jj * 16 + l15;
            float bias = bd[ncol];
            #pragma unroll
            for (int r = 0; r < 4; ++r)
                out[(size_t)(mb + r) * 512 + ncol] = c[ii][jj][r] + bias;
        }
    }
}

// ---------------- flash attention v16: fence-free MFMA/VALU interleave ----------------
// Lesson (R6): MFMA blocks its wave; T15 reordering is null. But a wave CAN issue VALU in the 32-cyc
// gaps of its own pipelined MFMA stream — IF no fence sits between them. v16 hoists the drain to the
// top of the E-phase (vmcnt(2): K(2t),K(2t+1),V(t-1),cb(t-1) all drained; K(2t+2),K(2t+3) stay in
// flight) and emits {2 QK MFMAs ; 2 exp2 of prev tile} x8 source-interleaved with ZERO fences, then
// pack+PV(prev). cb is a frag-major f32 table pre-scaled by log2e/8 (no unpack); exp = fma + v_exp_f32.
// FIFO (re-traced): prologue K0,K1,K2. t=0: E vmcnt(4), O vmcnt(12). steady E vmcnt(2), O none.
// t=31: E vmcnt(0), final softmax vmcnt(0). Logit: q*16, k*32, /8 head, *log2e -> fma const below.
__global__ __launch_bounds__(256, 2) void flash_attn(const unsigned short* __restrict__ qb,
                                                     const unsigned char* __restrict__ kpack8,
                                                     const unsigned short* __restrict__ vfrag,
                                                     const float* __restrict__ cbf_all,
                                                     const float* __restrict__ mixing,
                                                     _Float16* __restrict__ Opart,
                                                     float* __restrict__ lpart) {
    __shared__ char sK[4][8192];     // 4 x 8 KB fp8 K-chunk buffers (8 frag-pairs x 1024 B each)
    const int bid = blockIdx.x;
    const int half = bid & 1, b = (bid >> 1) & 1, h = (bid >> 2) & 7, qt = bid >> 5;
    const int tid = threadIdx.x, w = tid >> 6, lane = tid & 63;
    const int l31 = lane & 31, hi = lane >> 5;
    const int q0 = qt * 128 + w * 32;
    const unsigned short* vfb = vfrag + ((size_t)(b * H_ + h) * 64 + half * 32) * 2048;
    const float* cbfb = cbf_all + ((size_t)((b * 8 + h) * 64 + half * 32)) * 32 + hi * 16;
    const float* mixh = mixing + h * D_;
    const float SC = 1.44269504f / 4096.0f;   // log2e / (16*32*8)

    // ---- Q: bf16 rows -> x mixing (f32) -> fp8 B-frags in regs (frag i: d = i*16 + hi*8 + j) ----
    long qq[32];
    {
        const unsigned short* qrow = qb + ((size_t)(b * L_) + q0 + l31) * D_ + hi * 8;
        #pragma unroll
        for (int i = 0; i < 32; ++i) {
            ushort8 qv = *(const ushort8*)(qrow + i * 16);
            float4v ma = *(const float4v*)(mixh + i * 16 + hi * 8);
            float4v mb = *(const float4v*)(mixh + i * 16 + hi * 8 + 4);
            float v[8];
            v[0] = bf2f(qv[0]) * ma[0] * 16.f;
            v[1] = bf2f(qv[1]) * ma[1] * 16.f;
            v[2] = bf2f(qv[2]) * ma[2] * 16.f;
            v[3] = bf2f(qv[3]) * ma[3] * 16.f;
            v[4] = bf2f(qv[4]) * mb[0] * 16.f;
            v[5] = bf2f(qv[5]) * mb[1] * 16.f;
            v[6] = bf2f(qv[6]) * mb[2] * 16.f;
            v[7] = bf2f(qv[7]) * mb[3] * 16.f;
            qq[i] = pack8fp8(v);
        }
    }
    // Drain Q/mixing loads so the hand-counted vmcnt FIFO below starts clean.
    asm volatile("s_waitcnt vmcnt(0)" ::: "memory");

    f32x16 acco0, acco1;
    #pragma unroll
    for (int i = 0; i < 16; ++i) { acco0[i] = 0.f; acco1[i] = 0.f; }
    float lsum = 0.f;
    f32x16 aA0, aB0, aA1, aB1;           // S accumulators, 2 banks (even/odd tile)
    short8 av00, av01, av10, av11;       // V frags (bf16) in regs
    float4v cbf0, cbf1, cbf2, cbf3;      // cb tile (f32 frag-major, log2e-folded) in regs

    auto stageK = [&](int p) {
        const char* src = (const char*)kpack8 + (((size_t)(b * 64 + half * 32)) << 14) + (size_t)p * 8192;
        char* dst = &sK[p & 3][0];
        #pragma unroll
        for (int ii = 0; ii < 2; ++ii)
            async16(dst + w * 1024 + ii * 4096, src + w * 1024 + ii * 4096 + (size_t)lane * 16);
    };
    auto ldV = [&](int t) {
        const unsigned short* vp = vfb + (size_t)t * 2048 + lane * 8;
        av00 = *(const short8*)(vp);
        av01 = *(const short8*)(vp + 512);
        av10 = *(const short8*)(vp + 1024);
        av11 = *(const short8*)(vp + 1536);
        asm volatile("" ::: "memory");   // pin the 4 V loads at this FIFO position
    };
    auto ldCB = [&](int t) {
        const float* cp = cbfb + t * 32;
        cbf0 = *(const float4v*)(cp);
        cbf1 = *(const float4v*)(cp + 4);
        cbf2 = *(const float4v*)(cp + 8);
        cbf3 = *(const float4v*)(cp + 12);
        asm volatile("" ::: "memory");   // pin the 4 cb loads at this FIFO position
    };
    auto cbfv = [&](int R) -> float {    // R compile-time after unroll
        return (R < 4) ? cbf0[R & 3] : (R < 8) ? cbf1[R & 3] : (R < 12) ? cbf2[R & 3] : cbf3[R & 3];
    };
    // plain QK chunk (prologue tiles / odd phases)
    auto qk_chunk = [&](const char* buf, int qbase, f32x16& A, f32x16& B) {
        __builtin_amdgcn_s_setprio(1);
        #pragma unroll
        for (int p = 0; p < 8; ++p) {
            const long* ap = (const long*)&buf[p * 1024 + lane * 16];
            long a0 = ap[0], a1 = ap[1];
            A = __builtin_amdgcn_mfma_f32_32x32x16_fp8_fp8(a0, qq[qbase + 2 * p], A, 0, 0, 0);
            B = __builtin_amdgcn_mfma_f32_32x32x16_fp8_fp8(a1, qq[qbase + 2 * p + 1], B, 0, 0, 0);
        }
        __builtin_amdgcn_s_setprio(0);
    };
    // pack pex -> bf16 B-frags and run PV into acco
    auto pack_pv = [&](const float* pex) {
        union { unsigned int u[4]; short8 s8; } P0, P1;
        #pragma unroll
        for (int j = 0; j < 4; ++j) {
            P0.u[j] = __builtin_amdgcn_perm(__float_as_uint(pex[2 * j + 1]) + 0x8000u,
                                            __float_as_uint(pex[2 * j]) + 0x8000u, 0x07060302u);
            P1.u[j] = __builtin_amdgcn_perm(__float_as_uint(pex[8 + 2 * j + 1]) + 0x8000u,
                                            __float_as_uint(pex[8 + 2 * j]) + 0x8000u, 0x07060302u);
        }
        acco0 = __builtin_amdgcn_mfma_f32_32x32x16_bf16(av00, P0.s8, acco0, 0, 0, 0);
        acco0 = __builtin_amdgcn_mfma_f32_32x32x16_bf16(av01, P1.s8, acco0, 0, 0, 0);
        acco1 = __builtin_amdgcn_mfma_f32_32x32x16_bf16(av10, P0.s8, acco1, 0, 0, 0);
        acco1 = __builtin_amdgcn_mfma_f32_32x32x16_bf16(av11, P1.s8, acco1, 0, 0, 0);
    };
    // E-phase core: QK of current bank interleaved with softmax+PV of prev bank. NO fences inside.
    auto qk_sm = [&](const char* buf, f32x16& CA, f32x16& CB, const f32x16& PA, const f32x16& PB) {
        __builtin_amdgcn_s_setprio(1);
        float pex[16];
        float lsA = 0.f, lsB = 0.f;
        #pragma unroll
        for (int p = 0; p < 8; ++p) {
            const long* ap = (const long*)&buf[p * 1024 + lane * 16];
            long a0 = ap[0], a1 = ap[1];
            CA = __builtin_amdgcn_mfma_f32_32x32x16_fp8_fp8(a0, qq[2 * p], CA, 0, 0, 0);
            CB = __builtin_amdgcn_mfma_f32_32x32x16_fp8_fp8(a1, qq[2 * p + 1], CB, 0, 0, 0);
            float x0 = fmaf(PA[2 * p] + PB[2 * p], SC, cbfv(2 * p));
            float x1 = fmaf(PA[2 * p + 1] + PB[2 * p + 1], SC, cbfv(2 * p + 1));
            float e0, e1;
            asm("v_exp_f32 %0, %1" : "=v"(e0) : "v"(x0));
            asm("v_exp_f32 %0, %1" : "=v"(e1) : "v"(x1));
            pex[2 * p] = e0; pex[2 * p + 1] = e1;
            lsA += e0; lsB += e1;
        }
        lsum += lsA + lsB;
        pack_pv(pex);
        __builtin_amdgcn_s_setprio(0);
    };
    // final softmax+PV (no QK to interleave)
    auto sm_pv = [&](const f32x16& PA, const f32x16& PB) {
        float pex[16];
        float lsA = 0.f, lsB = 0.f;
        #pragma unroll
        for (int R = 0; R < 16; R += 2) {
            float x0 = fmaf(PA[R] + PB[R], SC, cbfv(R));
            float x1 = fmaf(PA[R + 1] + PB[R + 1], SC, cbfv(R + 1));
            float e0, e1;
            asm("v_exp_f32 %0, %1" : "=v"(e0) : "v"(x0));
            asm("v_exp_f32 %0, %1" : "=v"(e1) : "v"(x1));
            pex[R] = e0; pex[R + 1] = e1;
            lsA += e0; lsB += e1;
        }
        lsum += lsA + lsB;
        pack_pv(pex);
    };
    auto zero16 = [](f32x16& v) {
        #pragma unroll
        for (int i = 0; i < 16; ++i) v[i] = 0.f;
    };

    // ---- prologue: 3 K-chunks in flight (6 loads) ----
    stageK(0); stageK(1); stageK(2);

    // ---- t = 0 (bank0; no deferred softmax yet) ----
    zero16(aA0); zero16(aB0);
    asm volatile("s_waitcnt vmcnt(4)" ::: "memory");    // drain K0
    __builtin_amdgcn_s_barrier();
    stageK(3);
    qk_chunk(&sK[0][0], 0, aA0, aB0);
    ldV(0); ldCB(0);
    asm volatile("s_waitcnt vmcnt(12)" ::: "memory");   // drain K1 (queue: K1,K2,K3,V0,cb0)
    __builtin_amdgcn_s_barrier();
    stageK(4);
    qk_chunk(&sK[1][0], 16, aA0, aB0);

    // ---- main loop t = 1..30: E = {vmcnt(2); barrier; stageK; interleaved QK+softmax(prev); ldV/ldCB};
    //                            O = {barrier; stageK; QK odd chunk} ----
    #define E_TILE(T, CA, CB, PA, PB, BK)                                          \
        zero16(CA); zero16(CB);                                                    \
        asm volatile("s_waitcnt vmcnt(2)" ::: "memory");                           \
        __builtin_amdgcn_s_barrier();                                              \
        stageK(2 * (T) + 3);                                                       \
        qk_sm(&sK[BK][0], CA, CB, PA, PB);                                         \
        ldV(T); ldCB(T);
    #define O_TILE(T, CA, CB, BK)                                                  \
        __builtin_amdgcn_s_barrier();                                              \
        if ((T) < 30) stageK(2 * (T) + 4);                                         \
        qk_chunk(&sK[BK][0], 16, CA, CB);

    for (int tt = 1; tt < 30; tt += 2) {
        E_TILE(tt, aA1, aB1, aA0, aB0, 2);
        O_TILE(tt, aA1, aB1, 3);
        E_TILE(tt + 1, aA0, aB0, aA1, aB1, 0);
        O_TILE(tt + 1, aA0, aB0, 1);
    }
    #undef E_TILE
    #undef O_TILE

    // ---- t = 31 (bank1; deferred softmax of t=30 in bank0) ----
    {
        zero16(aA1); zero16(aB1);
        asm volatile("s_waitcnt vmcnt(0)" ::: "memory");    // queue only [K62,K63,V30,cb30] = 12: drain all
        __builtin_amdgcn_s_barrier();
        qk_sm(&sK[2][0], aA1, aB1, aA0, aB0);
        ldV(31); ldCB(31);
        __builtin_amdgcn_s_barrier();
        qk_chunk(&sK[3][0], 16, aA1, aB1);
        asm volatile("s_waitcnt vmcnt(0)" ::: "memory");    // drain V31,cb31
        sm_pv(aA1, aB1);
    }

    // ---- epilogue: lsum merge, fp16 O^T partials ----
    lsum += __shfl_xor(lsum, 32);
    if (hi == 0) lpart[(size_t)bid * 128 + w * 32 + l31] = lsum;
    #pragma unroll
    for (int R = 0; R < 16; ++R) {
        int dh = (R & 3) + 8 * (R >> 2) + 4 * hi;
        Opart[((size_t)bid * 64 + dh) * 128 + w * 32 + l31] = (_Float16)acco0[R];
        Opart[((size_t)bid * 64 + 32 + dh) * 128 + w * 32 + l31] = (_Float16)acco1[R];
    }
}

// ---------------- merge 2 split-S partials -> ctx (bf16) ----------------
__global__ __launch_bounds__(256) void merge_ctx(const _Float16* __restrict__ Opart,
                                                 const float* __restrict__ lpart,
                                                 unsigned short* __restrict__ ctxb) {
    int t = blockIdx.x * 256 + threadIdx.x;       // [0, 524288)
    int qq = t & 127, dh4 = (t >> 7) & 15, qt = (t >> 11) & 15, h = (t >> 15) & 7, b = t >> 18;
    int base = (qt << 5) | (h << 2) | (b << 1);   // flash bid with half=0
    float l = lpart[(size_t)base * 128 + qq] + lpart[(size_t)(base + 1) * 128 + qq];
    float inv = 1.f / l;
    ushort4v o;
    #pragma unroll
    for (int e = 0; e < 4; ++e) {
        int dh = dh4 * 4 + e;
        float v = (float)Opart[((size_t)base * 64 + dh) * 128 + qq]
                + (float)Opart[((size_t)(base + 1) * 64 + dh) * 128 + qq];
        o[e] = f2bf(v * inv);
    }
    *(ushort4v*)(ctxb + ((size_t)(b * L_) + qt * 128 + qq) * 512 + h * 64 + dh4 * 4) = o;
}

extern "C" void kernel_launch(void* const* d_in, const int* in_sizes, int n_in,
                              void* d_out, int out_size, void* d_ws, size_t ws_size,
                              hipStream_t stream) {
    (void)in_sizes; (void)n_in; (void)out_size; (void)ws_size;
    const float* x      = (const float*)d_in[0];
    const float* Wq     = (const float*)d_in[1];
    const float* Wk     = (const float*)d_in[2];
    const float* Wv     = (const float*)d_in[3];
    const float* Wb     = (const float*)d_in[4];
    const float* mixing = (const float*)d_in[5];
    const float* Wd     = (const float*)d_in[6];
    const float* bd     = (const float*)d_in[7];
    float* out = (float*)d_out;

    char* ws = (char*)d_ws;
    const size_t MiB = 1048576;
    unsigned short* xb     = (unsigned short*)(ws);                  // [0,4) MiB
    unsigned short* qb     = (unsigned short*)(ws + 4 * MiB);        // [4,8) bf16 q row-major
    unsigned char*  kpack8 = (unsigned char*)(ws + 8 * MiB);         // [8,10) fp8 K A-frags (x32)
    unsigned short* vfrag  = (unsigned short*)(ws + 10 * MiB);       // [10,14)
    unsigned short* ctxb   = (unsigned short*)(ws + 14 * MiB);       // [14,18)
    unsigned short* Wqb    = (unsigned short*)(ws + 18 * MiB);
    unsigned short* Wkb    = (unsigned short*)(ws + 18 * MiB + 512 * 1024);
    unsigned short* Wvb    = (unsigned short*)(ws + 19 * MiB);
    unsigned short* Wdb    = (unsigned short*)(ws + 19 * MiB + 512 * 1024);
    float* cbuf            = (float*)(ws + 20 * MiB);                // 128 KB (f32 frag-major)
    float* lpart           = (float*)(ws + 20 * MiB + 256 * 1024);   // 256 KB
    _Float16* Opart        = (_Float16*)(ws + 21 * MiB);             // [21,29) 8 MB

    cvt_cb<<<4096, 256, 0, stream>>>(x, Wq, Wk, Wv, Wd, Wb, xb, Wqb, Wkb, Wvb, Wdb, cbuf);
    gemm_qkv<<<dim3(32, 4, 3), 256, 0, stream>>>(xb, Wqb, Wkb, Wvb, qb, kpack8, vfrag);
    flash_attn<<<512, 256, 0, stream>>>(qb, kpack8, vfrag, cbuf, mixing, Opart, lpart);
    merge_ctx<<<2048, 256, 0, stream>>>(Opart, lpart, ctxb);
    gemm_out<<<dim3(32, 4), 256, 0, stream>>>(ctxb, Wdb, bd, out);
}

// Round 8
// 198.296 us; speedup vs baseline: 1.0180x; 1.0180x over previous
//
#include <hip/hip_runtime.h>

#define B_ 2
#define L_ 2048
#define D_ 512
#define H_ 8
#define S_ 2048

typedef __attribute__((ext_vector_type(8))) short short8;
typedef __attribute__((ext_vector_type(8))) unsigned short ushort8;
typedef __attribute__((ext_vector_type(4))) unsigned short ushort4v;
typedef __attribute__((ext_vector_type(4))) float f32x4;
typedef __attribute__((ext_vector_type(16))) float f32x16;
typedef __attribute__((ext_vector_type(4))) float float4v;

__device__ __forceinline__ unsigned short f2bf(float f) {
    unsigned u = __float_as_uint(f);
    u += 0x7FFF + ((u >> 16) & 1);   // RTNE
    return (unsigned short)(u >> 16);
}
__device__ __forceinline__ float bf2f(unsigned short s) {
    return __uint_as_float(((unsigned)s) << 16);
}
__device__ __forceinline__ unsigned char f2fp8(float f) {
    return (unsigned char)(__builtin_amdgcn_cvt_pk_fp8_f32(f, f, 0, false) & 0xff);
}
__device__ __forceinline__ long pack8fp8(const float* v) {
    int lo = __builtin_amdgcn_cvt_pk_fp8_f32(v[0], v[1], 0, false);
    lo = __builtin_amdgcn_cvt_pk_fp8_f32(v[2], v[3], lo, true);
    int hi = __builtin_amdgcn_cvt_pk_fp8_f32(v[4], v[5], 0, false);
    hi = __builtin_amdgcn_cvt_pk_fp8_f32(v[6], v[7], hi, true);
    union { int i[2]; long l; } u;
    u.i[0] = lo; u.i[1] = hi;
    return u.l;
}
__device__ __forceinline__ int swap23(int x) {
    return (x & ~12) | ((x & 4) << 1) | ((x & 8) >> 1);
}
__device__ __forceinline__ void async16(void* lds, const void* g) {
    __builtin_amdgcn_global_load_lds(
        (const __attribute__((address_space(1))) void*)(g),
        (__attribute__((address_space(3))) void*)(lds), 16, 0, 0);
}

// ---------------- fused: fp32->bf16 converts + content bias (frag-major f32, log2e/8-scaled) ----------------
__global__ __launch_bounds__(256) void cvt_cb(const float* __restrict__ x,
                                              const float* __restrict__ w0, const float* __restrict__ w1,
                                              const float* __restrict__ w2, const float* __restrict__ w3,
                                              const float* __restrict__ Wb,
                                              unsigned short* __restrict__ xb,
                                              unsigned short* __restrict__ d0, unsigned short* __restrict__ d1,
                                              unsigned short* __restrict__ d2, unsigned short* __restrict__ d3,
                                              float* __restrict__ cbf) {
    if (blockIdx.x < 3072) {
        int i = blockIdx.x * 256 + threadIdx.x;
        const float* s;
        unsigned short* d;
        int idx;
        if (i < 524288) { s = x; d = xb; idx = i; }
        else {
            int off = i - 524288;
            int wsel = off >> 16; idx = off & 65535;
            s = (wsel == 0) ? w0 : (wsel == 1) ? w1 : (wsel == 2) ? w2 : w3;
            d = (wsel == 0) ? d0 : (wsel == 1) ? d1 : (wsel == 2) ? d2 : d3;
        }
        float4v v = *(const float4v*)(s + (size_t)idx * 4);
        ushort4v o;
        o[0] = f2bf(v[0]); o[1] = f2bf(v[1]); o[2] = f2bf(v[2]); o[3] = f2bf(v[3]);
        *(ushort4v*)(d + (size_t)idx * 4) = o;
    } else {
        const int tid = threadIdx.x, w = tid >> 6, lane = tid & 63;
        const int row = (blockIdx.x - 3072) * 4 + w;
        const int h = lane >> 3, seg = lane & 7;
        const float* xp = x + (size_t)row * 512 + seg * 64;
        const float* wp = Wb + (size_t)h * 512 + seg * 64;
        float acc = 0.f;
        #pragma unroll
        for (int j = 0; j < 16; ++j) {
            float4v xv = *(const float4v*)(xp + j * 4);
            float4v wv = *(const float4v*)(wp + j * 4);
            acc += xv[0] * wv[0] + xv[1] * wv[1] + xv[2] * wv[2] + xv[3] * wv[3];
        }
        acc += __shfl_xor(acc, 1);
        acc += __shfl_xor(acc, 2);
        acc += __shfl_xor(acc, 4);
        if (seg == 0) {
            int b = row >> 11, s = row & 2047;
            int T = s >> 5, off = s & 31;
            int r2 = off & 3, k = off >> 2;
            int u = (k & 1) + ((k >> 2) << 1), hi2 = (k >> 1) & 1;
            int R = 4 * u + r2;
            cbf[((size_t)((b * 8 + h) * 64 + T)) * 32 + hi2 * 16 + R] = acc * 0.125f * 1.44269504f;
        }
    }
}

// ---------------- 128x128-tile GEMM core ----------------
__device__ __forceinline__ void gemm128_core(const unsigned short* __restrict__ Ap,
                                             const unsigned short* __restrict__ Bp,
                                             short* sA, short* sB, int tid, f32x4 c[4][4]) {
    const int w = tid >> 6, lane = tid & 63, quad = lane >> 4, l15 = lane & 15;
    const int wm = (w >> 1) * 64, wn = (w & 1) * 64;
    for (int kc = 0; kc < 8; ++kc) {
        __syncthreads();
        #pragma unroll
        for (int j = 0; j < 4; ++j) {
            int i = tid + j * 256;
            int row = i >> 3, seg = i & 7;
            *(ushort8*)&sA[row * 72 + seg * 8] = *(const ushort8*)(Ap + (size_t)row * 512 + kc * 64 + seg * 8);
            *(ushort8*)&sB[row * 72 + seg * 8] = *(const ushort8*)(Bp + (size_t)row * 512 + kc * 64 + seg * 8);
        }
        __syncthreads();
        #pragma unroll
        for (int ks = 0; ks < 2; ++ks) {
            short8 a[4], b[4];
            #pragma unroll
            for (int ii = 0; ii < 4; ++ii)
                a[ii] = *(const short8*)&sA[(wm + ii * 16 + l15) * 72 + ks * 32 + quad * 8];
            #pragma unroll
            for (int jj = 0; jj < 4; ++jj)
                b[jj] = *(const short8*)&sB[(wn + jj * 16 + l15) * 72 + ks * 32 + quad * 8];
            #pragma unroll
            for (int ii = 0; ii < 4; ++ii)
                #pragma unroll
                for (int jj = 0; jj < 4; ++jj)
                    c[ii][jj] = __builtin_amdgcn_mfma_f32_16x16x32_bf16(a[ii], b[jj], c[ii][jj], 0, 0, 0);
        }
    }
}

// ---------------- q,k,v projections ----------------
__global__ __launch_bounds__(256) void gemm_qkv(const unsigned short* __restrict__ xb,
                                                const unsigned short* __restrict__ Wqb,
                                                const unsigned short* __restrict__ Wkb,
                                                const unsigned short* __restrict__ Wvb,
                                                unsigned short* __restrict__ qb,
                                                unsigned char* __restrict__ kpack8,
                                                unsigned short* __restrict__ vfrag) {
    __shared__ short sA[128 * 72];
    __shared__ short sB[128 * 72];
    const int m0 = blockIdx.x * 128, n0 = blockIdx.y * 128, z = blockIdx.z;
    const unsigned short* Bsel = (z == 0) ? Wqb : ((z == 1) ? Wkb : Wvb);
    f32x4 c[4][4];
    #pragma unroll
    for (int ii = 0; ii < 4; ++ii)
        #pragma unroll
        for (int jj = 0; jj < 4; ++jj) { f32x4 zv = {0.f, 0.f, 0.f, 0.f}; c[ii][jj] = zv; }
    gemm128_core(xb + (size_t)m0 * 512, Bsel + (size_t)n0 * 512, sA, sB, threadIdx.x, c);
    const int tid = threadIdx.x, w = tid >> 6, lane = tid & 63, quad = lane >> 4, l15 = lane & 15;
    const int wm = (w >> 1) * 64, wn = (w & 1) * 64;
    #pragma unroll
    for (int ii = 0; ii < 4; ++ii) {
        const int mb = m0 + wm + ii * 16 + quad * 4;
        const int bb = mb >> 11;
        if (z == 0) {
            #pragma unroll
            for (int jj = 0; jj < 4; ++jj) {
                int ncol = n0 + wn + jj * 16 + l15;
                #pragma unroll
                for (int r = 0; r < 4; ++r)
                    qb[(size_t)(mb + r) * 512 + ncol] = f2bf(c[ii][jj][r]);
            }
        } else if (z == 1) {
            #pragma unroll
            for (int jj = 0; jj < 4; ++jj) {
                int d = n0 + wn + jj * 16 + l15;
                int pair = d >> 5, fh = (d >> 4) & 1, hid = (d >> 3) & 1, jq = d & 7;
                #pragma unroll
                for (int r = 0; r < 4; ++r) {
                    int s = (mb + r) & 2047;
                    int t = s >> 5, rr = swap23(s & 31);
                    kpack8[(((size_t)(bb * 64 + t) * 16 + pair) << 10)
                           + (hid * 32 + rr) * 16 + fh * 8 + jq] = f2fp8(c[ii][jj][r] * 32.f);
                }
            }
        } else {
            const int hh = (n0 + wn) >> 6;
            const int s = mb & 2047;
            #pragma unroll
            for (int jj = 0; jj < 4; ++jj) {
                int dh = jj * 16 + l15;
                ushort4v o;
                o[0] = f2bf(c[ii][jj][0]); o[1] = f2bf(c[ii][jj][1]);
                o[2] = f2bf(c[ii][jj][2]); o[3] = f2bf(c[ii][jj][3]);
                size_t blk = ((size_t)(bb * H_ + hh) * 64 + (s >> 5)) * 4
                           + ((dh >> 5) * 2 + ((s >> 4) & 1));
                *(ushort4v*)(vfrag + blk * 512 + (dh & 31) * 8 + ((s >> 3) & 1) * 256 + (s & 7)) = o;
            }
        }
    }
}

// ---------------- output projection ----------------
__global__ __launch_bounds__(256) void gemm_out(const unsigned short* __restrict__ ctxb,
                                                const unsigned short* __restrict__ Wdb,
                                                const float* __restrict__ bd,
                                                float* __restrict__ out) {
    __shared__ short sA[128 * 72];
    __shared__ short sB[128 * 72];
    const int m0 = blockIdx.x * 128, n0 = blockIdx.y * 128;
    f32x4 c[4][4];
    #pragma unroll
    for (int ii = 0; ii < 4; ++ii)
        #pragma unroll
        for (int jj = 0; jj < 4; ++jj) { f32x4 zv = {0.f, 0.f, 0.f, 0.f}; c[ii][jj] = zv; }
    gemm128_core(ctxb + (size_t)m0 * 512, Wdb + (size_t)n0 * 512, sA, sB, threadIdx.x, c);
    const int tid = threadIdx.x, w = tid >> 6, lane = tid & 63, quad = lane >> 4, l15 = lane & 15;
    const int wm = (w >> 1) * 64, wn = (w & 1) * 64;
    #pragma unroll
    for (int ii = 0; ii < 4; ++ii) {
        const int mb = m0 + wm + ii * 16 + quad * 4;
        #pragma unroll
        for (int jj = 0; jj < 4; ++jj) {
            int ncol = n0 + wn + jj * 16 + l15;
            float bias = bd[ncol];
            #pragma unroll
            for (int r = 0; r < 4; ++r)
                out[(size_t)(mb + r) * 512 + ncol] = c[ii][jj][r] + bias;
        }
    }
}

// ---------------- flash attention v17: ONE barrier/tile, 3x16KB LDS ring, full-tile interleave ----------------
// Per tile: {vmcnt(4); barrier; 32 QK MFMAs ⊗ softmax+PV(t-1) ⊗ mid ldV/ldCB(t); end stageK2(t+2)}.
// FIFO per phase: V(4),cb(4),K(4); steady vmcnt(4) leaves exactly the newest stage. Peels:
// phase0 vmcnt(4) (prologue K0,K1); phase31 vmcnt(0); final vmcnt(0). Barriers 32 (was 64).
__global__ __launch_bounds__(256, 2) void flash_attn(const unsigned short* __restrict__ qb,
                                                     const unsigned char* __restrict__ kpack8,
                                                     const unsigned short* __restrict__ vfrag,
                                                     const float* __restrict__ cbf_all,
                                                     const float* __restrict__ mixing,
                                                     _Float16* __restrict__ Opart,
                                                     float* __restrict__ lpart) {
    __shared__ char sK[3][16384];
    const int bid = blockIdx.x;
    const int half = bid & 1, b = (bid >> 1) & 1, h = (bid >> 2) & 7, qt = bid >> 5;
    const int tid = threadIdx.x, w = tid >> 6, lane = tid & 63;
    const int l31 = lane & 31, hi = lane >> 5;
    const int q0 = qt * 128 + w * 32;
    const unsigned short* vfb = vfrag + ((size_t)(b * H_ + h) * 64 + half * 32) * 2048;
    const float* cbfb = cbf_all + ((size_t)((b * 8 + h) * 64 + half * 32)) * 32 + hi * 16;
    const float* mixh = mixing + h * D_;
    const float SC = 1.44269504f / 4096.0f;

    long qq[32];
    {
        const unsigned short* qrow = qb + ((size_t)(b * L_) + q0 + l31) * D_ + hi * 8;
        #pragma unroll
        for (int i = 0; i < 32; ++i) {
            ushort8 qv = *(const ushort8*)(qrow + i * 16);
            float4v ma = *(const float4v*)(mixh + i * 16 + hi * 8);
            float4v mb = *(const float4v*)(mixh + i * 16 + hi * 8 + 4);
            float v[8];
            v[0] = bf2f(qv[0]) * ma[0] * 16.f;
            v[1] = bf2f(qv[1]) * ma[1] * 16.f;
            v[2] = bf2f(qv[2]) * ma[2] * 16.f;
            v[3] = bf2f(qv[3]) * ma[3] * 16.f;
            v[4] = bf2f(qv[4]) * mb[0] * 16.f;
            v[5] = bf2f(qv[5]) * mb[1] * 16.f;
            v[6] = bf2f(qv[6]) * mb[2] * 16.f;
            v[7] = bf2f(qv[7]) * mb[3] * 16.f;
            qq[i] = pack8fp8(v);
        }
    }
    asm volatile("s_waitcnt vmcnt(0)" ::: "memory");

    f32x16 acco0, acco1;
    #pragma unroll
    for (int i = 0; i < 16; ++i) { acco0[i] = 0.f; acco1[i] = 0.f; }
    float lsum = 0.f;
    f32x16 aA0, aB0, aA1, aB1;
    short8 av00, av01, av10, av11;
    float4v cbf0, cbf1, cbf2, cbf3;

    auto stageK2 = [&](int t, int bi) {
        const char* src = (const char*)kpack8 + (((size_t)(b * 64 + half * 32 + t)) << 14);
        char* dst = &sK[bi][0];
        #pragma unroll
        for (int ii = 0; ii < 4; ++ii)
            async16(dst + w * 1024 + ii * 4096, src + w * 1024 + ii * 4096 + (size_t)lane * 16);
    };
    auto ldV = [&](int t) {
        const unsigned short* vp = vfb + (size_t)t * 2048 + lane * 8;
        av00 = *(const short8*)(vp);
        av01 = *(const short8*)(vp + 512);
        av10 = *(const short8*)(vp + 1024);
        av11 = *(const short8*)(vp + 1536);
        asm volatile("" ::: "memory");
    };
    auto ldCB = [&](int t) {
        const float* cp = cbfb + t * 32;
        cbf0 = *(const float4v*)(cp);
        cbf1 = *(const float4v*)(cp + 4);
        cbf2 = *(const float4v*)(cp + 8);
        cbf3 = *(const float4v*)(cp + 12);
        asm volatile("" ::: "memory");
    };
    auto cbfv = [&](int R) -> float {
        return (R < 4) ? cbf0[R & 3] : (R < 8) ? cbf1[R & 3] : (R < 12) ? cbf2[R & 3] : cbf3[R & 3];
    };
    auto pack_pv = [&](const float* pex) {
        union { unsigned int u[4]; short8 s8; } P0, P1;
        #pragma unroll
        for (int j = 0; j < 4; ++j) {
            P0.u[j] = __builtin_amdgcn_perm(__float_as_uint(pex[2 * j + 1]) + 0x8000u,
                                            __float_as_uint(pex[2 * j]) + 0x8000u, 0x07060302u);
            P1.u[j] = __builtin_amdgcn_perm(__float_as_uint(pex[8 + 2 * j + 1]) + 0x8000u,
                                            __float_as_uint(pex[8 + 2 * j]) + 0x8000u, 0x07060302u);
        }
        acco0 = __builtin_amdgcn_mfma_f32_32x32x16_bf16(av00, P0.s8, acco0, 0, 0, 0);
        acco0 = __builtin_amdgcn_mfma_f32_32x32x16_bf16(av01, P1.s8, acco0, 0, 0, 0);
        acco1 = __builtin_amdgcn_mfma_f32_32x32x16_bf16(av10, P0.s8, acco1, 0, 0, 0);
        acco1 = __builtin_amdgcn_mfma_f32_32x32x16_bf16(av11, P1.s8, acco1, 0, 0, 0);
    };
    auto tile_fused = [&](const char* buf, int T, f32x16& CA, f32x16& CB,
                          const f32x16& PA, const f32x16& PB) {
        __builtin_amdgcn_s_setprio(1);
        float pex[16];
        float lsA = 0.f, lsB = 0.f;
        #pragma unroll
        for (int fp = 0; fp < 16; ++fp) {
            const long* ap = (const long*)&buf[fp * 1024 + lane * 16];
            long a0 = ap[0], a1 = ap[1];
            CA = __builtin_amdgcn_mfma_f32_32x32x16_fp8_fp8(a0, qq[2 * fp], CA, 0, 0, 0);
            CB = __builtin_amdgcn_mfma_f32_32x32x16_fp8_fp8(a1, qq[2 * fp + 1], CB, 0, 0, 0);
            if (fp < 8) {
                float x0 = fmaf(PA[2 * fp] + PB[2 * fp], SC, cbfv(2 * fp));
                float x1 = fmaf(PA[2 * fp + 1] + PB[2 * fp + 1], SC, cbfv(2 * fp + 1));
                float e0, e1;
                asm("v_exp_f32 %0, %1" : "=v"(e0) : "v"(x0));
                asm("v_exp_f32 %0, %1" : "=v"(e1) : "v"(x1));
                pex[2 * fp] = e0; pex[2 * fp + 1] = e1;
                lsA += e0; lsB += e1;
            }
            if (fp == 8) { lsum += lsA + lsB; pack_pv(pex); }
            if (fp == 9)  ldV(T);
            if (fp == 10) ldCB(T);
        }
        __builtin_amdgcn_s_setprio(0);
    };
    auto tile_plain = [&](const char* buf, int T, f32x16& CA, f32x16& CB) {
        __builtin_amdgcn_s_setprio(1);
        #pragma unroll
        for (int fp = 0; fp < 16; ++fp) {
            const long* ap = (const long*)&buf[fp * 1024 + lane * 16];
            long a0 = ap[0], a1 = ap[1];
            CA = __builtin_amdgcn_mfma_f32_32x32x16_fp8_fp8(a0, qq[2 * fp], CA, 0, 0, 0);
            CB = __builtin_amdgcn_mfma_f32_32x32x16_fp8_fp8(a1, qq[2 * fp + 1], CB, 0, 0, 0);
            if (fp == 9)  ldV(T);
            if (fp == 10) ldCB(T);
        }
        __builtin_amdgcn_s_setprio(0);
    };
    auto sm_pv = [&](const f32x16& PA, const f32x16& PB) {
        float pex[16];
        float lsA = 0.f, lsB = 0.f;
        #pragma unroll
        for (int R = 0; R < 16; R += 2) {
            float x0 = fmaf(PA[R] + PB[R], SC, cbfv(R));
            float x1 = fmaf(PA[R + 1] + PB[R + 1], SC, cbfv(R + 1));
            float e0, e1;
            asm("v_exp_f32 %0, %1" : "=v"(e0) : "v"(x0));
            asm("v_exp_f32 %0, %1" : "=v"(e1) : "v"(x1));
            pex[R] = e0; pex[R + 1] = e1;
            lsA += e0; lsB += e1;
        }
        lsum += lsA + lsB;
        pack_pv(pex);
    };
    auto zero16 = [](f32x16& v) {
        #pragma unroll
        for (int i = 0; i < 16; ++i) v[i] = 0.f;
    };

    // ---- prologue: 2 K-tiles in flight ----
    stageK2(0, 0); stageK2(1, 1);

    // ---- phase 0 (bank0, buf0) ----
    zero16(aA0); zero16(aB0);
    asm volatile("s_waitcnt vmcnt(4)" ::: "memory");
    __builtin_amdgcn_s_barrier();
    tile_plain(&sK[0][0], 0, aA0, aB0);
    stageK2(2, 2);

    // ---- phases 1..30 (ring: tile t -> buf t%3; stage t+2 -> buf (t+2)%3) ----
    int cur = 1;
    for (int t = 1; t <= 30; t += 2) {
        zero16(aA1); zero16(aB1);
        asm volatile("s_waitcnt vmcnt(4)" ::: "memory");
        __builtin_amdgcn_s_barrier();
        tile_fused(&sK[cur][0], t, aA1, aB1, aA0, aB0);
        if (t + 2 <= 31) stageK2(t + 2, (cur + 2 >= 3) ? cur - 1 : cur + 2);
        cur = (cur == 2) ? 0 : cur + 1;

        zero16(aA0); zero16(aB0);
        asm volatile("s_waitcnt vmcnt(4)" ::: "memory");
        __builtin_amdgcn_s_barrier();
        tile_fused(&sK[cur][0], t + 1, aA0, aB0, aA1, aB1);
        if (t + 3 <= 31) stageK2(t + 3, (cur + 2 >= 3) ? cur - 1 : cur + 2);
        cur = (cur == 2) ? 0 : cur + 1;
    }

    // ---- phase 31 (bank1, buf cur=1; deferred softmax of 30 in bank0) ----
    {
        zero16(aA1); zero16(aB1);
        asm volatile("s_waitcnt vmcnt(0)" ::: "memory");
        __builtin_amdgcn_s_barrier();
        tile_fused(&sK[cur][0], 31, aA1, aB1, aA0, aB0);
        asm volatile("s_waitcnt vmcnt(0)" ::: "memory");
        sm_pv(aA1, aB1);
    }

    // ---- epilogue ----
    lsum += __shfl_xor(lsum, 32);
    if (hi == 0) lpart[(size_t)bid * 128 + w * 32 + l31] = lsum;
    #pragma unroll
    for (int R = 0; R < 16; ++R) {
        int dh = (R & 3) + 8 * (R >> 2) + 4 * hi;
        Opart[((size_t)bid * 64 + dh) * 128 + w * 32 + l31] = (_Float16)acco0[R];
        Opart[((size_t)bid * 64 + 32 + dh) * 128 + w * 32 + l31] = (_Float16)acco1[R];
    }
}

// ---------------- merge 2 split-S partials -> ctx (bf16) ----------------
__global__ __launch_bounds__(256) void merge_ctx(const _Float16* __restrict__ Opart,
                                                 const float* __restrict__ lpart,
                                                 unsigned short* __restrict__ ctxb) {
    int t = blockIdx.x * 256 + threadIdx.x;
    int qq = t & 127, dh4 = (t >> 7) & 15, qt = (t >> 11) & 15, h = (t >> 15) & 7, b = t >> 18;
    int base = (qt << 5) | (h << 2) | (b << 1);
    float l = lpart[(size_t)base * 128 + qq] + lpart[(size_t)(base + 1) * 128 + qq];
    float inv = 1.f / l;
    ushort4v o;
    #pragma unroll
    for (int e = 0; e < 4; ++e) {
        int dh = dh4 * 4 + e;
        float v = (float)Opart[((size_t)base * 64 + dh) * 128 + qq]
                + (float)Opart[((size_t)(base + 1) * 64 + dh) * 128 + qq];
        o[e] = f2bf(v * inv);
    }
    *(ushort4v*)(ctxb + ((size_t)(b * L_) + qt * 128 + qq) * 512 + h * 64 + dh4 * 4) = o;
}

extern "C" void kernel_launch(void* const* d_in, const int* in_sizes, int n_in,
                              void* d_out, int out_size, void* d_ws, size_t ws_size,
                              hipStream_t stream) {
    (void)in_sizes; (void)n_in; (void)out_size; (void)ws_size;
    const float* x      = (const float*)d_in[0];
    const float* Wq     = (const float*)d_in[1];
    const float* Wk     = (const float*)d_in[2];
    const float* Wv     = (const float*)d_in[3];
    const float* Wb     = (const float*)d_in[4];
    const float* mixing = (const float*)d_in[5];
    const float* Wd     = (const float*)d_in[6];
    const float* bd     = (const float*)d_in[7];
    float* out = (float*)d_out;

    char* ws = (char*)d_ws;
    const size_t MiB = 1048576;
    unsigned short* xb     = (unsigned short*)(ws);
    unsigned short* qb     = (unsigned short*)(ws + 4 * MiB);
    unsigned char*  kpack8 = (unsigned char*)(ws + 8 * MiB);
    unsigned short* vfrag  = (unsigned short*)(ws + 10 * MiB);
    unsigned short* ctxb   = (unsigned short*)(ws + 14 * MiB);
    unsigned short* Wqb    = (unsigned short*)(ws + 18 * MiB);
    unsigned short* Wkb    = (unsigned short*)(ws + 18 * MiB + 512 * 1024);
    unsigned short* Wvb    = (unsigned short*)(ws + 19 * MiB);
    unsigned short* Wdb    = (unsigned short*)(ws + 19 * MiB + 512 * 1024);
    float* cbuf            = (float*)(ws + 20 * MiB);
    float* lpart           = (float*)(ws + 20 * MiB + 256 * 1024);
    _Float16* Opart        = (_Float16*)(ws + 21 * MiB);

    cvt_cb<<<4096, 256, 0, stream>>>(x, Wq, Wk, Wv, Wd, Wb, xb, Wqb, Wkb, Wvb, Wdb, cbuf);
    gemm_qkv<<<dim3(32, 4, 3), 256, 0, stream>>>(xb, Wqb, Wkb, Wvb, qb, kpack8, vfrag);
    flash_attn<<<512, 256, 0, stream>>>(qb, kpack8, vfrag, cbuf, mixing, Opart, lpart);
    merge_ctx<<<2048, 256, 0, stream>>>(Opart, lpart, ctxb);
    gemm_out<<<dim3(32, 4), 256, 0, stream>>>(ctxb, Wdb, bd, out);
}

// Round 10
// 197.041 us; speedup vs baseline: 1.0244x; 1.0064x over previous
//
#include <hip/hip_runtime.h>

#define B_ 2
#define L_ 2048
#define D_ 512
#define H_ 8
#define S_ 2048

typedef __attribute__((ext_vector_type(8))) short short8;
typedef __attribute__((ext_vector_type(8))) unsigned short ushort8;
typedef __attribute__((ext_vector_type(4))) unsigned short ushort4v;
typedef __attribute__((ext_vector_type(4))) float f32x4;
typedef __attribute__((ext_vector_type(16))) float f32x16;
typedef __attribute__((ext_vector_type(4))) float float4v;
typedef __attribute__((ext_vector_type(8))) _Float16 half8;

__device__ __forceinline__ unsigned short f2bf(float f) {
    unsigned u = __float_as_uint(f);
    u += 0x7FFF + ((u >> 16) & 1);   // RTNE
    return (unsigned short)(u >> 16);
}
__device__ __forceinline__ float bf2f(unsigned short s) {
    return __uint_as_float(((unsigned)s) << 16);
}
__device__ __forceinline__ unsigned char f2fp8(float f) {
    return (unsigned char)(__builtin_amdgcn_cvt_pk_fp8_f32(f, f, 0, false) & 0xff);
}
__device__ __forceinline__ long pack8fp8(const float* v) {
    int lo = __builtin_amdgcn_cvt_pk_fp8_f32(v[0], v[1], 0, false);
    lo = __builtin_amdgcn_cvt_pk_fp8_f32(v[2], v[3], lo, true);
    int hi = __builtin_amdgcn_cvt_pk_fp8_f32(v[4], v[5], 0, false);
    hi = __builtin_amdgcn_cvt_pk_fp8_f32(v[6], v[7], hi, true);
    union { int i[2]; long l; } u;
    u.i[0] = lo; u.i[1] = hi;
    return u.l;
}
__device__ __forceinline__ int swap23(int x) {
    return (x & ~12) | ((x & 4) << 1) | ((x & 8) >> 1);
}
__device__ __forceinline__ void async16(void* lds, const void* g) {
    __builtin_amdgcn_global_load_lds(
        (const __attribute__((address_space(1))) void*)(g),
        (__attribute__((address_space(3))) void*)(lds), 16, 0, 0);
}

// ---------------- fused: fp32->bf16 converts + content bias (frag-major f32, log2e/8-scaled) ----------------
__global__ __launch_bounds__(256) void cvt_cb(const float* __restrict__ x,
                                              const float* __restrict__ w0, const float* __restrict__ w1,
                                              const float* __restrict__ w2, const float* __restrict__ w3,
                                              const float* __restrict__ Wb,
                                              unsigned short* __restrict__ xb,
                                              unsigned short* __restrict__ d0, unsigned short* __restrict__ d1,
                                              unsigned short* __restrict__ d2, unsigned short* __restrict__ d3,
                                              float* __restrict__ cbf) {
    if (blockIdx.x < 3072) {
        int i = blockIdx.x * 256 + threadIdx.x;
        const float* s;
        unsigned short* d;
        int idx;
        if (i < 524288) { s = x; d = xb; idx = i; }
        else {
            int off = i - 524288;
            int wsel = off >> 16; idx = off & 65535;
            s = (wsel == 0) ? w0 : (wsel == 1) ? w1 : (wsel == 2) ? w2 : w3;
            d = (wsel == 0) ? d0 : (wsel == 1) ? d1 : (wsel == 2) ? d2 : d3;
        }
        float4v v = *(const float4v*)(s + (size_t)idx * 4);
        ushort4v o;
        o[0] = f2bf(v[0]); o[1] = f2bf(v[1]); o[2] = f2bf(v[2]); o[3] = f2bf(v[3]);
        *(ushort4v*)(d + (size_t)idx * 4) = o;
    } else {
        const int tid = threadIdx.x, w = tid >> 6, lane = tid & 63;
        const int row = (blockIdx.x - 3072) * 4 + w;
        const int h = lane >> 3, seg = lane & 7;
        const float* xp = x + (size_t)row * 512 + seg * 64;
        const float* wp = Wb + (size_t)h * 512 + seg * 64;
        float acc = 0.f;
        #pragma unroll
        for (int j = 0; j < 16; ++j) {
            float4v xv = *(const float4v*)(xp + j * 4);
            float4v wv = *(const float4v*)(wp + j * 4);
            acc += xv[0] * wv[0] + xv[1] * wv[1] + xv[2] * wv[2] + xv[3] * wv[3];
        }
        acc += __shfl_xor(acc, 1);
        acc += __shfl_xor(acc, 2);
        acc += __shfl_xor(acc, 4);
        if (seg == 0) {
            int b = row >> 11, s = row & 2047;
            int T = s >> 5, off = s & 31;
            int r2 = off & 3, k = off >> 2;
            int u = (k & 1) + ((k >> 2) << 1), hi2 = (k >> 1) & 1;
            int R = 4 * u + r2;
            cbf[((size_t)((b * 8 + h) * 64 + T)) * 32 + hi2 * 16 + R] = acc * 0.125f * 1.44269504f;
        }
    }
}

// ---------------- 128x128-tile GEMM core ----------------
__device__ __forceinline__ void gemm128_core(const unsigned short* __restrict__ Ap,
                                             const unsigned short* __restrict__ Bp,
                                             short* sA, short* sB, int tid, f32x4 c[4][4]) {
    const int w = tid >> 6, lane = tid & 63, quad = lane >> 4, l15 = lane & 15;
    const int wm = (w >> 1) * 64, wn = (w & 1) * 64;
    for (int kc = 0; kc < 8; ++kc) {
        __syncthreads();
        #pragma unroll
        for (int j = 0; j < 4; ++j) {
            int i = tid + j * 256;
            int row = i >> 3, seg = i & 7;
            *(ushort8*)&sA[row * 72 + seg * 8] = *(const ushort8*)(Ap + (size_t)row * 512 + kc * 64 + seg * 8);
            *(ushort8*)&sB[row * 72 + seg * 8] = *(const ushort8*)(Bp + (size_t)row * 512 + kc * 64 + seg * 8);
        }
        __syncthreads();
        #pragma unroll
        for (int ks = 0; ks < 2; ++ks) {
            short8 a[4], b[4];
            #pragma unroll
            for (int ii = 0; ii < 4; ++ii)
                a[ii] = *(const short8*)&sA[(wm + ii * 16 + l15) * 72 + ks * 32 + quad * 8];
            #pragma unroll
            for (int jj = 0; jj < 4; ++jj)
                b[jj] = *(const short8*)&sB[(wn + jj * 16 + l15) * 72 + ks * 32 + quad * 8];
            #pragma unroll
            for (int ii = 0; ii < 4; ++ii)
                #pragma unroll
                for (int jj = 0; jj < 4; ++jj)
                    c[ii][jj] = __builtin_amdgcn_mfma_f32_16x16x32_bf16(a[ii], b[jj], c[ii][jj], 0, 0, 0);
        }
    }
}

// ---------------- q,k,v projections ----------------
__global__ __launch_bounds__(256) void gemm_qkv(const unsigned short* __restrict__ xb,
                                                const unsigned short* __restrict__ Wqb,
                                                const unsigned short* __restrict__ Wkb,
                                                const unsigned short* __restrict__ Wvb,
                                                unsigned short* __restrict__ qb,
                                                unsigned char* __restrict__ kpack8,
                                                unsigned short* __restrict__ vfrag) {
    __shared__ short sA[128 * 72];
    __shared__ short sB[128 * 72];
    const int m0 = blockIdx.x * 128, n0 = blockIdx.y * 128, z = blockIdx.z;
    const unsigned short* Bsel = (z == 0) ? Wqb : ((z == 1) ? Wkb : Wvb);
    f32x4 c[4][4];
    #pragma unroll
    for (int ii = 0; ii < 4; ++ii)
        #pragma unroll
        for (int jj = 0; jj < 4; ++jj) { f32x4 zv = {0.f, 0.f, 0.f, 0.f}; c[ii][jj] = zv; }
    gemm128_core(xb + (size_t)m0 * 512, Bsel + (size_t)n0 * 512, sA, sB, threadIdx.x, c);
    const int tid = threadIdx.x, w = tid >> 6, lane = tid & 63, quad = lane >> 4, l15 = lane & 15;
    const int wm = (w >> 1) * 64, wn = (w & 1) * 64;
    #pragma unroll
    for (int ii = 0; ii < 4; ++ii) {
        const int mb = m0 + wm + ii * 16 + quad * 4;
        const int bb = mb >> 11;
        if (z == 0) {
            #pragma unroll
            for (int jj = 0; jj < 4; ++jj) {
                int ncol = n0 + wn + jj * 16 + l15;
                #pragma unroll
                for (int r = 0; r < 4; ++r)
                    qb[(size_t)(mb + r) * 512 + ncol] = f2bf(c[ii][jj][r]);
            }
        } else if (z == 1) {
            #pragma unroll
            for (int jj = 0; jj < 4; ++jj) {
                int d = n0 + wn + jj * 16 + l15;
                int pair = d >> 5, fh = (d >> 4) & 1, hid = (d >> 3) & 1, jq = d & 7;
                #pragma unroll
                for (int r = 0; r < 4; ++r) {
                    int s = (mb + r) & 2047;
                    int t = s >> 5, rr = swap23(s & 31);
                    kpack8[(((size_t)(bb * 64 + t) * 16 + pair) << 10)
                           + (hid * 32 + rr) * 16 + fh * 8 + jq] = f2fp8(c[ii][jj][r] * 32.f);
                }
            }
        } else {
            const int hh = (n0 + wn) >> 6;
            const int s = mb & 2047;
            #pragma unroll
            for (int jj = 0; jj < 4; ++jj) {
                int dh = jj * 16 + l15;
                ushort4v o;
                o[0] = f2bf(c[ii][jj][0]); o[1] = f2bf(c[ii][jj][1]);
                o[2] = f2bf(c[ii][jj][2]); o[3] = f2bf(c[ii][jj][3]);
                size_t blk = ((size_t)(bb * H_ + hh) * 64 + (s >> 5)) * 4
                           + ((dh >> 5) * 2 + ((s >> 4) & 1));
                *(ushort4v*)(vfrag + blk * 512 + (dh & 31) * 8 + ((s >> 3) & 1) * 256 + (s & 7)) = o;
            }
        }
    }
}

// ---------------- fused merge + output projection ----------------
// A-stage merges the two split-S partials on the fly: Opart is q-major ([bid][q 128][dh 64] fp16),
// so chunk (row, kc, seg) = Opart[base(qt,h=kc,b)][qq][seg*8..+8] + same for base+1, x rcp(l0+l1).
// R9 bug fixed: B staging must use (n0 + row), not row (gemm128_core got Wdb + n0*512 pre-offset).
__global__ __launch_bounds__(256) void gemm_out(const _Float16* __restrict__ Opart,
                                                const float* __restrict__ lpart,
                                                const unsigned short* __restrict__ Wdb,
                                                const float* __restrict__ bd,
                                                float* __restrict__ out) {
    __shared__ short sA[128 * 72];
    __shared__ short sB[128 * 72];
    const int m0 = blockIdx.x * 128, n0 = blockIdx.y * 128;
    const int tid = threadIdx.x, w = tid >> 6, lane = tid & 63, quad = lane >> 4, l15 = lane & 15;
    const int wm = (w >> 1) * 64, wn = (w & 1) * 64;
    f32x4 c[4][4];
    #pragma unroll
    for (int ii = 0; ii < 4; ++ii)
        #pragma unroll
        for (int jj = 0; jj < 4; ++jj) { f32x4 zv = {0.f, 0.f, 0.f, 0.f}; c[ii][jj] = zv; }
    for (int kc = 0; kc < 8; ++kc) {
        __syncthreads();
        #pragma unroll
        for (int j = 0; j < 4; ++j) {
            int i = tid + j * 256;
            int row = i >> 3, seg = i & 7;
            // ---- A: merged ctx[m0+row][kc*64 + seg*8 .. +8] ----
            int gq = m0 + row;
            int b = gq >> 11, ql = gq & 2047, qq = ql & 127;
            int base = ((ql >> 7) << 5) | (kc << 2) | (b << 1);
            const _Float16* o0 = Opart + ((size_t)base << 13) + qq * 64 + seg * 8;
            float l = lpart[(size_t)base * 128 + qq] + lpart[(size_t)(base + 1) * 128 + qq];
            float inv = __builtin_amdgcn_rcpf(l);
            half8 v0 = *(const half8*)o0;
            half8 v1 = *(const half8*)(o0 + 8192);
            ushort8 ov;
            #pragma unroll
            for (int e = 0; e < 8; ++e)
                ov[e] = f2bf(((float)v0[e] + (float)v1[e]) * inv);
            *(ushort8*)&sA[row * 72 + seg * 8] = ov;
            // ---- B: Wd row (n0 + row) ----
            *(ushort8*)&sB[row * 72 + seg * 8] =
                *(const ushort8*)(Wdb + (size_t)(n0 + row) * 512 + kc * 64 + seg * 8);
        }
        __syncthreads();
        #pragma unroll
        for (int ks = 0; ks < 2; ++ks) {
            short8 a[4], b2[4];
            #pragma unroll
            for (int ii = 0; ii < 4; ++ii)
                a[ii] = *(const short8*)&sA[(wm + ii * 16 + l15) * 72 + ks * 32 + quad * 8];
            #pragma unroll
            for (int jj = 0; jj < 4; ++jj)
                b2[jj] = *(const short8*)&sB[(wn + jj * 16 + l15) * 72 + ks * 32 + quad * 8];
            #pragma unroll
            for (int ii = 0; ii < 4; ++ii)
                #pragma unroll
                for (int jj = 0; jj < 4; ++jj)
                    c[ii][jj] = __builtin_amdgcn_mfma_f32_16x16x32_bf16(a[ii], b2[jj], c[ii][jj], 0, 0, 0);
        }
    }
    #pragma unroll
    for (int ii = 0; ii < 4; ++ii) {
        const int mb = m0 + wm + ii * 16 + quad * 4;
        #pragma unroll
        for (int jj = 0; jj < 4; ++jj) {
            int ncol = n0 + wn + jj * 16 + l15;
            float bias = bd[ncol];
            #pragma unroll
            for (int r = 0; r < 4; ++r)
                out[(size_t)(mb + r) * 512 + ncol] = c[ii][jj][r] + bias;
        }
    }
}

// ---------------- flash attention v18: v17 core + q-major Opart epilogue (LDS transpose) ----------------
__global__ __launch_bounds__(256, 2) void flash_attn(const unsigned short* __restrict__ qb,
                                                     const unsigned char* __restrict__ kpack8,
                                                     const unsigned short* __restrict__ vfrag,
                                                     const float* __restrict__ cbf_all,
                                                     const float* __restrict__ mixing,
                                                     _Float16* __restrict__ Opart,
                                                     float* __restrict__ lpart) {
    __shared__ char sK[3][16384];
    const int bid = blockIdx.x;
    const int half = bid & 1, b = (bid >> 1) & 1, h = (bid >> 2) & 7, qt = bid >> 5;
    const int tid = threadIdx.x, w = tid >> 6, lane = tid & 63;
    const int l31 = lane & 31, hi = lane >> 5;
    const int q0 = qt * 128 + w * 32;
    const unsigned short* vfb = vfrag + ((size_t)(b * H_ + h) * 64 + half * 32) * 2048;
    const float* cbfb = cbf_all + ((size_t)((b * 8 + h) * 64 + half * 32)) * 32 + hi * 16;
    const float* mixh = mixing + h * D_;
    const float SC = 1.44269504f / 4096.0f;

    long qq[32];
    {
        const unsigned short* qrow = qb + ((size_t)(b * L_) + q0 + l31) * D_ + hi * 8;
        #pragma unroll
        for (int i = 0; i < 32; ++i) {
            ushort8 qv = *(const ushort8*)(qrow + i * 16);
            float4v ma = *(const float4v*)(mixh + i * 16 + hi * 8);
            float4v mb = *(const float4v*)(mixh + i * 16 + hi * 8 + 4);
            float v[8];
            v[0] = bf2f(qv[0]) * ma[0] * 16.f;
            v[1] = bf2f(qv[1]) * ma[1] * 16.f;
            v[2] = bf2f(qv[2]) * ma[2] * 16.f;
            v[3] = bf2f(qv[3]) * ma[3] * 16.f;
            v[4] = bf2f(qv[4]) * mb[0] * 16.f;
            v[5] = bf2f(qv[5]) * mb[1] * 16.f;
            v[6] = bf2f(qv[6]) * mb[2] * 16.f;
            v[7] = bf2f(qv[7]) * mb[3] * 16.f;
            qq[i] = pack8fp8(v);
        }
    }
    asm volatile("s_waitcnt vmcnt(0)" ::: "memory");

    f32x16 acco0, acco1;
    #pragma unroll
    for (int i = 0; i < 16; ++i) { acco0[i] = 0.f; acco1[i] = 0.f; }
    float lsum = 0.f;
    f32x16 aA0, aB0, aA1, aB1;
    short8 av00, av01, av10, av11;
    float4v cbf0, cbf1, cbf2, cbf3;

    auto stageK2 = [&](int t, int bi) {
        const char* src = (const char*)kpack8 + (((size_t)(b * 64 + half * 32 + t)) << 14);
        char* dst = &sK[bi][0];
        #pragma unroll
        for (int ii = 0; ii < 4; ++ii)
            async16(dst + w * 1024 + ii * 4096, src + w * 1024 + ii * 4096 + (size_t)lane * 16);
    };
    auto ldV = [&](int t) {
        const unsigned short* vp = vfb + (size_t)t * 2048 + lane * 8;
        av00 = *(const short8*)(vp);
        av01 = *(const short8*)(vp + 512);
        av10 = *(const short8*)(vp + 1024);
        av11 = *(const short8*)(vp + 1536);
        asm volatile("" ::: "memory");
    };
    auto ldCB = [&](int t) {
        const float* cp = cbfb + t * 32;
        cbf0 = *(const float4v*)(cp);
        cbf1 = *(const float4v*)(cp + 4);
        cbf2 = *(const float4v*)(cp + 8);
        cbf3 = *(const float4v*)(cp + 12);
        asm volatile("" ::: "memory");
    };
    auto cbfv = [&](int R) -> float {
        return (R < 4) ? cbf0[R & 3] : (R < 8) ? cbf1[R & 3] : (R < 12) ? cbf2[R & 3] : cbf3[R & 3];
    };
    auto pack_pv = [&](const float* pex) {
        union { unsigned int u[4]; short8 s8; } P0, P1;
        #pragma unroll
        for (int j = 0; j < 4; ++j) {
            P0.u[j] = __builtin_amdgcn_perm(__float_as_uint(pex[2 * j + 1]) + 0x8000u,
                                            __float_as_uint(pex[2 * j]) + 0x8000u, 0x07060302u);
            P1.u[j] = __builtin_amdgcn_perm(__float_as_uint(pex[8 + 2 * j + 1]) + 0x8000u,
                                            __float_as_uint(pex[8 + 2 * j]) + 0x8000u, 0x07060302u);
        }
        acco0 = __builtin_amdgcn_mfma_f32_32x32x16_bf16(av00, P0.s8, acco0, 0, 0, 0);
        acco0 = __builtin_amdgcn_mfma_f32_32x32x16_bf16(av01, P1.s8, acco0, 0, 0, 0);
        acco1 = __builtin_amdgcn_mfma_f32_32x32x16_bf16(av10, P0.s8, acco1, 0, 0, 0);
        acco1 = __builtin_amdgcn_mfma_f32_32x32x16_bf16(av11, P1.s8, acco1, 0, 0, 0);
    };
    auto tile_fused = [&](const char* buf, int T, f32x16& CA, f32x16& CB,
                          const f32x16& PA, const f32x16& PB) {
        __builtin_amdgcn_s_setprio(1);
        float pex[16];
        float lsA = 0.f, lsB = 0.f;
        #pragma unroll
        for (int fp = 0; fp < 16; ++fp) {
            const long* ap = (const long*)&buf[fp * 1024 + lane * 16];
            long a0 = ap[0], a1 = ap[1];
            CA = __builtin_amdgcn_mfma_f32_32x32x16_fp8_fp8(a0, qq[2 * fp], CA, 0, 0, 0);
            CB = __builtin_amdgcn_mfma_f32_32x32x16_fp8_fp8(a1, qq[2 * fp + 1], CB, 0, 0, 0);
            if (fp < 8) {
                float x0 = fmaf(PA[2 * fp] + PB[2 * fp], SC, cbfv(2 * fp));
                float x1 = fmaf(PA[2 * fp + 1] + PB[2 * fp + 1], SC, cbfv(2 * fp + 1));
                float e0, e1;
                asm("v_exp_f32 %0, %1" : "=v"(e0) : "v"(x0));
                asm("v_exp_f32 %0, %1" : "=v"(e1) : "v"(x1));
                pex[2 * fp] = e0; pex[2 * fp + 1] = e1;
                lsA += e0; lsB += e1;
            }
            if (fp == 8) { lsum += lsA + lsB; pack_pv(pex); }
            if (fp == 9)  ldV(T);
            if (fp == 10) ldCB(T);
        }
        __builtin_amdgcn_s_setprio(0);
    };
    auto tile_plain = [&](const char* buf, int T, f32x16& CA, f32x16& CB) {
        __builtin_amdgcn_s_setprio(1);
        #pragma unroll
        for (int fp = 0; fp < 16; ++fp) {
            const long* ap = (const long*)&buf[fp * 1024 + lane * 16];
            long a0 = ap[0], a1 = ap[1];
            CA = __builtin_amdgcn_mfma_f32_32x32x16_fp8_fp8(a0, qq[2 * fp], CA, 0, 0, 0);
            CB = __builtin_amdgcn_mfma_f32_32x32x16_fp8_fp8(a1, qq[2 * fp + 1], CB, 0, 0, 0);
            if (fp == 9)  ldV(T);
            if (fp == 10) ldCB(T);
        }
        __builtin_amdgcn_s_setprio(0);
    };
    auto sm_pv = [&](const f32x16& PA, const f32x16& PB) {
        float pex[16];
        float lsA = 0.f, lsB = 0.f;
        #pragma unroll
        for (int R = 0; R < 16; R += 2) {
            float x0 = fmaf(PA[R] + PB[R], SC, cbfv(R));
            float x1 = fmaf(PA[R + 1] + PB[R + 1], SC, cbfv(R + 1));
            float e0, e1;
            asm("v_exp_f32 %0, %1" : "=v"(e0) : "v"(x0));
            asm("v_exp_f32 %0, %1" : "=v"(e1) : "v"(x1));
            pex[R] = e0; pex[R + 1] = e1;
            lsA += e0; lsB += e1;
        }
        lsum += lsA + lsB;
        pack_pv(pex);
    };
    auto zero16 = [](f32x16& v) {
        #pragma unroll
        for (int i = 0; i < 16; ++i) v[i] = 0.f;
    };

    // ---- prologue: 2 K-tiles in flight ----
    stageK2(0, 0); stageK2(1, 1);

    // ---- phase 0 (bank0, buf0) ----
    zero16(aA0); zero16(aB0);
    asm volatile("s_waitcnt vmcnt(4)" ::: "memory");
    __builtin_amdgcn_s_barrier();
    tile_plain(&sK[0][0], 0, aA0, aB0);
    stageK2(2, 2);

    // ---- phases 1..30 (ring: tile t -> buf t%3; stage t+2 -> buf (t+2)%3) ----
    int cur = 1;
    for (int t = 1; t <= 30; t += 2) {
        zero16(aA1); zero16(aB1);
        asm volatile("s_waitcnt vmcnt(4)" ::: "memory");
        __builtin_amdgcn_s_barrier();
        tile_fused(&sK[cur][0], t, aA1, aB1, aA0, aB0);
        if (t + 2 <= 31) stageK2(t + 2, (cur + 2 >= 3) ? cur - 1 : cur + 2);
        cur = (cur == 2) ? 0 : cur + 1;

        zero16(aA0); zero16(aB0);
        asm volatile("s_waitcnt vmcnt(4)" ::: "memory");
        __builtin_amdgcn_s_barrier();
        tile_fused(&sK[cur][0], t + 1, aA0, aB0, aA1, aB1);
        if (t + 3 <= 31) stageK2(t + 3, (cur + 2 >= 3) ? cur - 1 : cur + 2);
        cur = (cur == 2) ? 0 : cur + 1;
    }

    // ---- phase 31 (bank1, buf cur=1; deferred softmax of 30 in bank0) ----
    {
        zero16(aA1); zero16(aB1);
        asm volatile("s_waitcnt vmcnt(0)" ::: "memory");
        __builtin_amdgcn_s_barrier();
        tile_fused(&sK[cur][0], 31, aA1, aB1, aA0, aB0);
        asm volatile("s_waitcnt vmcnt(0)" ::: "memory");
        sm_pv(aA1, aB1);
    }

    // ---- epilogue: lsum; transpose O^T -> Opart[bid][q][dh] via LDS; coalesced 16 KB dump ----
    lsum += __shfl_xor(lsum, 32);
    if (hi == 0) lpart[(size_t)bid * 128 + w * 32 + l31] = lsum;
    __syncthreads();                                   // all waves done with the sK ring
    {
        _Float16* sO = (_Float16*)&sK[0][0];           // [128][72] halves = 18 KB (stride 16B-aligned)
        const int q = w * 32 + l31;
        #pragma unroll
        for (int R = 0; R < 16; ++R) {
            int dh = (R & 3) + 8 * (R >> 2) + 4 * hi;
            sO[q * 72 + dh]      = (_Float16)acco0[R];
            sO[q * 72 + 32 + dh] = (_Float16)acco1[R];
        }
        // wave w wrote q in [32w, 32w+32); thread tid dumps q = tid>>1 in the same range ->
        // intra-wave RAW through LDS (DS ops in-order within a wave), no barrier needed
        const int qd = tid >> 1, hf = tid & 1;
        _Float16* dst = Opart + ((size_t)bid << 13) + qd * 64 + hf * 32;
        const _Float16* srcp = sO + qd * 72 + hf * 32;
        #pragma unroll
        for (int k = 0; k < 4; ++k)
            *(half8*)(dst + k * 8) = *(const half8*)(srcp + k * 8);
    }
}

extern "C" void kernel_launch(void* const* d_in, const int* in_sizes, int n_in,
                              void* d_out, int out_size, void* d_ws, size_t ws_size,
                              hipStream_t stream) {
    (void)in_sizes; (void)n_in; (void)out_size; (void)ws_size;
    const float* x      = (const float*)d_in[0];
    const float* Wq     = (const float*)d_in[1];
    const float* Wk     = (const float*)d_in[2];
    const float* Wv     = (const float*)d_in[3];
    const float* Wb     = (const float*)d_in[4];
    const float* mixing = (const float*)d_in[5];
    const float* Wd     = (const float*)d_in[6];
    const float* bd     = (const float*)d_in[7];
    float* out = (float*)d_out;

    char* ws = (char*)d_ws;
    const size_t MiB = 1048576;
    unsigned short* xb     = (unsigned short*)(ws);                  // [0,4) MiB
    unsigned short* qb     = (unsigned short*)(ws + 4 * MiB);        // [4,8) bf16 q row-major
    unsigned char*  kpack8 = (unsigned char*)(ws + 8 * MiB);         // [8,10) fp8 K A-frags (x32)
    unsigned short* vfrag  = (unsigned short*)(ws + 10 * MiB);       // [10,14)
    unsigned short* Wqb    = (unsigned short*)(ws + 18 * MiB);
    unsigned short* Wkb    = (unsigned short*)(ws + 18 * MiB + 512 * 1024);
    unsigned short* Wvb    = (unsigned short*)(ws + 19 * MiB);
    unsigned short* Wdb    = (unsigned short*)(ws + 19 * MiB + 512 * 1024);
    float* cbuf            = (float*)(ws + 20 * MiB);                // 128 KB (f32 frag-major)
    float* lpart           = (float*)(ws + 20 * MiB + 256 * 1024);   // 256 KB
    _Float16* Opart        = (_Float16*)(ws + 21 * MiB);             // [21,29) 8 MB, q-major

    cvt_cb<<<4096, 256, 0, stream>>>(x, Wq, Wk, Wv, Wd, Wb, xb, Wqb, Wkb, Wvb, Wdb, cbuf);
    gemm_qkv<<<dim3(32, 4, 3), 256, 0, stream>>>(xb, Wqb, Wkb, Wvb, qb, kpack8, vfrag);
    flash_attn<<<512, 256, 0, stream>>>(qb, kpack8, vfrag, cbuf, mixing, Opart, lpart);
    gemm_out<<<dim3(32, 4), 256, 0, stream>>>(Opart, lpart, Wdb, bd, out);
}

// Round 11
// 194.974 us; speedup vs baseline: 1.0353x; 1.0106x over previous
//
#include <hip/hip_runtime.h>

#define B_ 2
#define L_ 2048
#define D_ 512
#define H_ 8
#define S_ 2048

typedef __attribute__((ext_vector_type(8))) short short8;
typedef __attribute__((ext_vector_type(8))) unsigned short ushort8;
typedef __attribute__((ext_vector_type(4))) unsigned short ushort4v;
typedef __attribute__((ext_vector_type(4))) float f32x4;
typedef __attribute__((ext_vector_type(16))) float f32x16;
typedef __attribute__((ext_vector_type(4))) float float4v;
typedef __attribute__((ext_vector_type(8))) _Float16 half8;
typedef __attribute__((ext_vector_type(4))) _Float16 half4;

__device__ __forceinline__ unsigned short f2bf(float f) {
    unsigned u = __float_as_uint(f);
    u += 0x7FFF + ((u >> 16) & 1);   // RTNE
    return (unsigned short)(u >> 16);
}
__device__ __forceinline__ float bf2f(unsigned short s) {
    return __uint_as_float(((unsigned)s) << 16);
}
__device__ __forceinline__ unsigned char f2fp8(float f) {
    return (unsigned char)(__builtin_amdgcn_cvt_pk_fp8_f32(f, f, 0, false) & 0xff);
}
__device__ __forceinline__ long pack8fp8(const float* v) {
    int lo = __builtin_amdgcn_cvt_pk_fp8_f32(v[0], v[1], 0, false);
    lo = __builtin_amdgcn_cvt_pk_fp8_f32(v[2], v[3], lo, true);
    int hi = __builtin_amdgcn_cvt_pk_fp8_f32(v[4], v[5], 0, false);
    hi = __builtin_amdgcn_cvt_pk_fp8_f32(v[6], v[7], hi, true);
    union { int i[2]; long l; } u;
    u.i[0] = lo; u.i[1] = hi;
    return u.l;
}
__device__ __forceinline__ int swap23(int x) {
    return (x & ~12) | ((x & 4) << 1) | ((x & 8) >> 1);
}
// async global->LDS, 16B per lane; LDS arg = WAVE-UNIFORM base (HW adds lane*16); global arg per-lane
__device__ __forceinline__ void async16(void* lds, const void* g) {
    __builtin_amdgcn_global_load_lds(
        (const __attribute__((address_space(1))) void*)(g),
        (__attribute__((address_space(3))) void*)(lds), 16, 0, 0);
}

// ---------------- fused: fp32->bf16 converts + content bias (frag-major f32, log2e/8-scaled) ----------------
__global__ __launch_bounds__(256) void cvt_cb(const float* __restrict__ x,
                                              const float* __restrict__ w0, const float* __restrict__ w1,
                                              const float* __restrict__ w2, const float* __restrict__ w3,
                                              const float* __restrict__ Wb,
                                              unsigned short* __restrict__ xb,
                                              unsigned short* __restrict__ d0, unsigned short* __restrict__ d1,
                                              unsigned short* __restrict__ d2, unsigned short* __restrict__ d3,
                                              float* __restrict__ cbf) {
    if (blockIdx.x < 3072) {
        int i = blockIdx.x * 256 + threadIdx.x;
        const float* s;
        unsigned short* d;
        int idx;
        if (i < 524288) { s = x; d = xb; idx = i; }
        else {
            int off = i - 524288;
            int wsel = off >> 16; idx = off & 65535;
            s = (wsel == 0) ? w0 : (wsel == 1) ? w1 : (wsel == 2) ? w2 : w3;
            d = (wsel == 0) ? d0 : (wsel == 1) ? d1 : (wsel == 2) ? d2 : d3;
        }
        float4v v = *(const float4v*)(s + (size_t)idx * 4);
        ushort4v o;
        o[0] = f2bf(v[0]); o[1] = f2bf(v[1]); o[2] = f2bf(v[2]); o[3] = f2bf(v[3]);
        *(ushort4v*)(d + (size_t)idx * 4) = o;
    } else {
        const int tid = threadIdx.x, w = tid >> 6, lane = tid & 63;
        const int row = (blockIdx.x - 3072) * 4 + w;
        const int h = lane >> 3, seg = lane & 7;
        const float* xp = x + (size_t)row * 512 + seg * 64;
        const float* wp = Wb + (size_t)h * 512 + seg * 64;
        float acc = 0.f;
        #pragma unroll
        for (int j = 0; j < 16; ++j) {
            float4v xv = *(const float4v*)(xp + j * 4);
            float4v wv = *(const float4v*)(wp + j * 4);
            acc += xv[0] * wv[0] + xv[1] * wv[1] + xv[2] * wv[2] + xv[3] * wv[3];
        }
        acc += __shfl_xor(acc, 1);
        acc += __shfl_xor(acc, 2);
        acc += __shfl_xor(acc, 4);
        if (seg == 0) {
            int b = row >> 11, s = row & 2047;
            int T = s >> 5, off = s & 31;
            int r2 = off & 3, k = off >> 2;
            int u = (k & 1) + ((k >> 2) << 1), hi2 = (k >> 1) & 1;
            int R = 4 * u + r2;
            cbf[((size_t)((b * 8 + h) * 64 + T)) * 32 + hi2 * 16 + R] = acc * 0.125f * 1.44269504f;
        }
    }
}

// ---------------- 128x128-tile GEMM core (register-staged; used by gemm_out) ----------------
__device__ __forceinline__ void gemm128_core(const unsigned short* __restrict__ Ap,
                                             const unsigned short* __restrict__ Bp,
                                             short* sA, short* sB, int tid, f32x4 c[4][4]) {
    const int w = tid >> 6, lane = tid & 63, quad = lane >> 4, l15 = lane & 15;
    const int wm = (w >> 1) * 64, wn = (w & 1) * 64;
    for (int kc = 0; kc < 8; ++kc) {
        __syncthreads();
        #pragma unroll
        for (int j = 0; j < 4; ++j) {
            int i = tid + j * 256;
            int row = i >> 3, seg = i & 7;
            *(ushort8*)&sA[row * 72 + seg * 8] = *(const ushort8*)(Ap + (size_t)row * 512 + kc * 64 + seg * 8);
            *(ushort8*)&sB[row * 72 + seg * 8] = *(const ushort8*)(Bp + (size_t)row * 512 + kc * 64 + seg * 8);
        }
        __syncthreads();
        #pragma unroll
        for (int ks = 0; ks < 2; ++ks) {
            short8 a[4], b[4];
            #pragma unroll
            for (int ii = 0; ii < 4; ++ii)
                a[ii] = *(const short8*)&sA[(wm + ii * 16 + l15) * 72 + ks * 32 + quad * 8];
            #pragma unroll
            for (int jj = 0; jj < 4; ++jj)
                b[jj] = *(const short8*)&sB[(wn + jj * 16 + l15) * 72 + ks * 32 + quad * 8];
            #pragma unroll
            for (int ii = 0; ii < 4; ++ii)
                #pragma unroll
                for (int jj = 0; jj < 4; ++jj)
                    c[ii][jj] = __builtin_amdgcn_mfma_f32_16x16x32_bf16(a[ii], b[jj], c[ii][jj], 0, 0, 0);
        }
    }
}

// ---------------- q,k,v projections: async-DMA staged core (m97 pattern), 1 barrier/kc ----------------
// LDS tiles linear [row 128][chunk 8][16B]; chunk c of row r holds GLOBAL chunk (c ^ (r&7))
// (rule #21: linear dest + pre-swizzled source + swizzled read). Double-buffered: 64 KB.
__global__ __launch_bounds__(256) void gemm_qkv(const unsigned short* __restrict__ xb,
                                                const unsigned short* __restrict__ Wqb,
                                                const unsigned short* __restrict__ Wkb,
                                                const unsigned short* __restrict__ Wvb,
                                                unsigned short* __restrict__ qb,
                                                unsigned char* __restrict__ kpack8,
                                                unsigned short* __restrict__ vfrag) {
    __shared__ char sAB[2][32768];   // [buf][ A 16KB | B 16KB ]
    const int m0 = blockIdx.x * 128, n0 = blockIdx.y * 128, z = blockIdx.z;
    const unsigned short* Bsel = (z == 0) ? Wqb : ((z == 1) ? Wkb : Wvb);
    const int tid = threadIdx.x, w = tid >> 6, lane = tid & 63, quad = lane >> 4, l15 = lane & 15;
    const int wm = (w >> 1) * 64, wn = (w & 1) * 64;
    const char* Ab = (const char*)(xb + (size_t)m0 * 512);
    const char* Bb = (const char*)(Bsel + (size_t)n0 * 512);
    // staging: slot(j) = j*256 + tid -> row = j*32 + (tid>>3), c = tid&7; source chunk = c ^ (row&7)
    const int srow = tid >> 3;
    const int csw = (tid & 7) ^ (srow & 7);
    const size_t srcOff = (size_t)srow * 1024 + (size_t)csw * 16;   // bytes
    auto stage = [&](int kc, int bi) {
        char* ba = &sAB[bi][0];
        #pragma unroll
        for (int j = 0; j < 4; ++j)
            async16(ba + j * 4096 + w * 1024, Ab + (size_t)j * 32768 + kc * 128 + srcOff);
        #pragma unroll
        for (int j = 0; j < 4; ++j)
            async16(ba + 16384 + j * 4096 + w * 1024, Bb + (size_t)j * 32768 + kc * 128 + srcOff);
    };

    f32x4 c[4][4];
    #pragma unroll
    for (int ii = 0; ii < 4; ++ii)
        #pragma unroll
        for (int jj = 0; jj < 4; ++jj) { f32x4 zv = {0.f, 0.f, 0.f, 0.f}; c[ii][jj] = zv; }

    stage(0, 0);
    for (int kc = 0; kc < 8; ++kc) {
        __syncthreads();                       // vmcnt(0)+lgkmcnt(0)+barrier: drains own DMA, syncs buf
        if (kc < 7) stage(kc + 1, (kc + 1) & 1);
        const char* tA = &sAB[kc & 1][0];
        const char* tB = &sAB[kc & 1][16384];
        #pragma unroll
        for (int ks = 0; ks < 2; ++ks) {
            short8 a[4], b[4];
            #pragma unroll
            for (int ii = 0; ii < 4; ++ii) {
                int row = wm + ii * 16 + l15;
                a[ii] = *(const short8*)(tA + row * 128 + (((ks * 4 + quad) ^ (l15 & 7)) * 16));
            }
            #pragma unroll
            for (int jj = 0; jj < 4; ++jj) {
                int row = wn + jj * 16 + l15;
                b[jj] = *(const short8*)(tB + row * 128 + (((ks * 4 + quad) ^ (l15 & 7)) * 16));
            }
            #pragma unroll
            for (int ii = 0; ii < 4; ++ii)
                #pragma unroll
                for (int jj = 0; jj < 4; ++jj)
                    c[ii][jj] = __builtin_amdgcn_mfma_f32_16x16x32_bf16(a[ii], b[jj], c[ii][jj], 0, 0, 0);
        }
    }

    // ---- epilogues (identical to R10) ----
    #pragma unroll
    for (int ii = 0; ii < 4; ++ii) {
        const int mb = m0 + wm + ii * 16 + quad * 4;
        const int bb = mb >> 11;
        if (z == 0) {
            #pragma unroll
            for (int jj = 0; jj < 4; ++jj) {
                int ncol = n0 + wn + jj * 16 + l15;
                #pragma unroll
                for (int r = 0; r < 4; ++r)
                    qb[(size_t)(mb + r) * 512 + ncol] = f2bf(c[ii][jj][r]);
            }
        } else if (z == 1) {
            #pragma unroll
            for (int jj = 0; jj < 4; ++jj) {
                int d = n0 + wn + jj * 16 + l15;
                int pair = d >> 5, fh = (d >> 4) & 1, hid = (d >> 3) & 1, jq = d & 7;
                #pragma unroll
                for (int r = 0; r < 4; ++r) {
                    int s = (mb + r) & 2047;
                    int t = s >> 5, rr = swap23(s & 31);
                    kpack8[(((size_t)(bb * 64 + t) * 16 + pair) << 10)
                           + (hid * 32 + rr) * 16 + fh * 8 + jq] = f2fp8(c[ii][jj][r] * 32.f);
                }
            }
        } else {
            const int hh = (n0 + wn) >> 6;
            const int s = mb & 2047;
            #pragma unroll
            for (int jj = 0; jj < 4; ++jj) {
                int dh = jj * 16 + l15;
                ushort4v o;
                o[0] = f2bf(c[ii][jj][0]); o[1] = f2bf(c[ii][jj][1]);
                o[2] = f2bf(c[ii][jj][2]); o[3] = f2bf(c[ii][jj][3]);
                size_t blk = ((size_t)(bb * H_ + hh) * 64 + (s >> 5)) * 4
                           + ((dh >> 5) * 2 + ((s >> 4) & 1));
                *(ushort4v*)(vfrag + blk * 512 + (dh & 31) * 8 + ((s >> 3) & 1) * 256 + (s & 7)) = o;
            }
        }
    }
}

// ---------------- fused merge + output projection ----------------
__global__ __launch_bounds__(256) void gemm_out(const _Float16* __restrict__ Opart,
                                                const float* __restrict__ lpart,
                                                const unsigned short* __restrict__ Wdb,
                                                const float* __restrict__ bd,
                                                float* __restrict__ out) {
    __shared__ short sA[128 * 72];
    __shared__ short sB[128 * 72];
    const int m0 = blockIdx.x * 128, n0 = blockIdx.y * 128;
    const int tid = threadIdx.x, w = tid >> 6, lane = tid & 63, quad = lane >> 4, l15 = lane & 15;
    const int wm = (w >> 1) * 64, wn = (w & 1) * 64;
    f32x4 c[4][4];
    #pragma unroll
    for (int ii = 0; ii < 4; ++ii)
        #pragma unroll
        for (int jj = 0; jj < 4; ++jj) { f32x4 zv = {0.f, 0.f, 0.f, 0.f}; c[ii][jj] = zv; }
    for (int kc = 0; kc < 8; ++kc) {
        __syncthreads();
        #pragma unroll
        for (int j = 0; j < 4; ++j) {
            int i = tid + j * 256;
            int row = i >> 3, seg = i & 7;
            int gq = m0 + row;
            int b = gq >> 11, ql = gq & 2047, qq = ql & 127;
            int base = ((ql >> 7) << 5) | (kc << 2) | (b << 1);
            const _Float16* o0 = Opart + ((size_t)base << 13) + qq * 64 + seg * 8;
            float l = lpart[(size_t)base * 128 + qq] + lpart[(size_t)(base + 1) * 128 + qq];
            float inv = __builtin_amdgcn_rcpf(l);
            half8 v0 = *(const half8*)o0;
            half8 v1 = *(const half8*)(o0 + 8192);
            ushort8 ov;
            #pragma unroll
            for (int e = 0; e < 8; ++e)
                ov[e] = f2bf(((float)v0[e] + (float)v1[e]) * inv);
            *(ushort8*)&sA[row * 72 + seg * 8] = ov;
            *(ushort8*)&sB[row * 72 + seg * 8] =
                *(const ushort8*)(Wdb + (size_t)(n0 + row) * 512 + kc * 64 + seg * 8);
        }
        __syncthreads();
        #pragma unroll
        for (int ks = 0; ks < 2; ++ks) {
            short8 a[4], b2[4];
            #pragma unroll
            for (int ii = 0; ii < 4; ++ii)
                a[ii] = *(const short8*)&sA[(wm + ii * 16 + l15) * 72 + ks * 32 + quad * 8];
            #pragma unroll
            for (int jj = 0; jj < 4; ++jj)
                b2[jj] = *(const short8*)&sB[(wn + jj * 16 + l15) * 72 + ks * 32 + quad * 8];
            #pragma unroll
            for (int ii = 0; ii < 4; ++ii)
                #pragma unroll
                for (int jj = 0; jj < 4; ++jj)
                    c[ii][jj] = __builtin_amdgcn_mfma_f32_16x16x32_bf16(a[ii], b2[jj], c[ii][jj], 0, 0, 0);
        }
    }
    #pragma unroll
    for (int ii = 0; ii < 4; ++ii) {
        const int mb = m0 + wm + ii * 16 + quad * 4;
        #pragma unroll
        for (int jj = 0; jj < 4; ++jj) {
            int ncol = n0 + wn + jj * 16 + l15;
            float bias = bd[ncol];
            #pragma unroll
            for (int r = 0; r < 4; ++r)
                out[(size_t)(mb + r) * 512 + ncol] = c[ii][jj][r] + bias;
        }
    }
}

// ---------------- flash attention v19: v18 core + lean epilogue (no barrier, b64-packed writes) ----------------
__global__ __launch_bounds__(256, 2) void flash_attn(const unsigned short* __restrict__ qb,
                                                     const unsigned char* __restrict__ kpack8,
                                                     const unsigned short* __restrict__ vfrag,
                                                     const float* __restrict__ cbf_all,
                                                     const float* __restrict__ mixing,
                                                     _Float16* __restrict__ Opart,
                                                     float* __restrict__ lpart) {
    __shared__ char sK[3][16384];
    const int bid = blockIdx.x;
    const int half = bid & 1, b = (bid >> 1) & 1, h = (bid >> 2) & 7, qt = bid >> 5;
    const int tid = threadIdx.x, w = tid >> 6, lane = tid & 63;
    const int l31 = lane & 31, hi = lane >> 5;
    const int q0 = qt * 128 + w * 32;
    const unsigned short* vfb = vfrag + ((size_t)(b * H_ + h) * 64 + half * 32) * 2048;
    const float* cbfb = cbf_all + ((size_t)((b * 8 + h) * 64 + half * 32)) * 32 + hi * 16;
    const float* mixh = mixing + h * D_;
    const float SC = 1.44269504f / 4096.0f;

    long qq[32];
    {
        const unsigned short* qrow = qb + ((size_t)(b * L_) + q0 + l31) * D_ + hi * 8;
        #pragma unroll
        for (int i = 0; i < 32; ++i) {
            ushort8 qv = *(const ushort8*)(qrow + i * 16);
            float4v ma = *(const float4v*)(mixh + i * 16 + hi * 8);
            float4v mb = *(const float4v*)(mixh + i * 16 + hi * 8 + 4);
            float v[8];
            v[0] = bf2f(qv[0]) * ma[0] * 16.f;
            v[1] = bf2f(qv[1]) * ma[1] * 16.f;
            v[2] = bf2f(qv[2]) * ma[2] * 16.f;
            v[3] = bf2f(qv[3]) * ma[3] * 16.f;
            v[4] = bf2f(qv[4]) * mb[0] * 16.f;
            v[5] = bf2f(qv[5]) * mb[1] * 16.f;
            v[6] = bf2f(qv[6]) * mb[2] * 16.f;
            v[7] = bf2f(qv[7]) * mb[3] * 16.f;
            qq[i] = pack8fp8(v);
        }
    }
    asm volatile("s_waitcnt vmcnt(0)" ::: "memory");

    f32x16 acco0, acco1;
    #pragma unroll
    for (int i = 0; i < 16; ++i) { acco0[i] = 0.f; acco1[i] = 0.f; }
    float lsum = 0.f;
    f32x16 aA0, aB0, aA1, aB1;
    short8 av00, av01, av10, av11;
    float4v cbf0, cbf1, cbf2, cbf3;

    auto stageK2 = [&](int t, int bi) {
        const char* src = (const char*)kpack8 + (((size_t)(b * 64 + half * 32 + t)) << 14);
        char* dst = &sK[bi][0];
        #pragma unroll
        for (int ii = 0; ii < 4; ++ii)
            async16(dst + w * 1024 + ii * 4096, src + w * 1024 + ii * 4096 + (size_t)lane * 16);
    };
    auto ldV = [&](int t) {
        const unsigned short* vp = vfb + (size_t)t * 2048 + lane * 8;
        av00 = *(const short8*)(vp);
        av01 = *(const short8*)(vp + 512);
        av10 = *(const short8*)(vp + 1024);
        av11 = *(const short8*)(vp + 1536);
        asm volatile("" ::: "memory");
    };
    auto ldCB = [&](int t) {
        const float* cp = cbfb + t * 32;
        cbf0 = *(const float4v*)(cp);
        cbf1 = *(const float4v*)(cp + 4);
        cbf2 = *(const float4v*)(cp + 8);
        cbf3 = *(const float4v*)(cp + 12);
        asm volatile("" ::: "memory");
    };
    auto cbfv = [&](int R) -> float {
        return (R < 4) ? cbf0[R & 3] : (R < 8) ? cbf1[R & 3] : (R < 12) ? cbf2[R & 3] : cbf3[R & 3];
    };
    auto pack_pv = [&](const float* pex) {
        union { unsigned int u[4]; short8 s8; } P0, P1;
        #pragma unroll
        for (int j = 0; j < 4; ++j) {
            P0.u[j] = __builtin_amdgcn_perm(__float_as_uint(pex[2 * j + 1]) + 0x8000u,
                                            __float_as_uint(pex[2 * j]) + 0x8000u, 0x07060302u);
            P1.u[j] = __builtin_amdgcn_perm(__float_as_uint(pex[8 + 2 * j + 1]) + 0x8000u,
                                            __float_as_uint(pex[8 + 2 * j]) + 0x8000u, 0x07060302u);
        }
        acco0 = __builtin_amdgcn_mfma_f32_32x32x16_bf16(av00, P0.s8, acco0, 0, 0, 0);
        acco0 = __builtin_amdgcn_mfma_f32_32x32x16_bf16(av01, P1.s8, acco0, 0, 0, 0);
        acco1 = __builtin_amdgcn_mfma_f32_32x32x16_bf16(av10, P0.s8, acco1, 0, 0, 0);
        acco1 = __builtin_amdgcn_mfma_f32_32x32x16_bf16(av11, P1.s8, acco1, 0, 0, 0);
    };
    auto tile_fused = [&](const char* buf, int T, f32x16& CA, f32x16& CB,
                          const f32x16& PA, const f32x16& PB) {
        __builtin_amdgcn_s_setprio(1);
        float pex[16];
        float lsA = 0.f, lsB = 0.f;
        #pragma unroll
        for (int fp = 0; fp < 16; ++fp) {
            const long* ap = (const long*)&buf[fp * 1024 + lane * 16];
            long a0 = ap[0], a1 = ap[1];
            CA = __builtin_amdgcn_mfma_f32_32x32x16_fp8_fp8(a0, qq[2 * fp], CA, 0, 0, 0);
            CB = __builtin_amdgcn_mfma_f32_32x32x16_fp8_fp8(a1, qq[2 * fp + 1], CB, 0, 0, 0);
            if (fp < 8) {
                float x0 = fmaf(PA[2 * fp] + PB[2 * fp], SC, cbfv(2 * fp));
                float x1 = fmaf(PA[2 * fp + 1] + PB[2 * fp + 1], SC, cbfv(2 * fp + 1));
                float e0, e1;
                asm("v_exp_f32 %0, %1" : "=v"(e0) : "v"(x0));
                asm("v_exp_f32 %0, %1" : "=v"(e1) : "v"(x1));
                pex[2 * fp] = e0; pex[2 * fp + 1] = e1;
                lsA += e0; lsB += e1;
            }
            if (fp == 8) { lsum += lsA + lsB; pack_pv(pex); }
            if (fp == 9)  ldV(T);
            if (fp == 10) ldCB(T);
        }
        __builtin_amdgcn_s_setprio(0);
    };
    auto tile_plain = [&](const char* buf, int T, f32x16& CA, f32x16& CB) {
        __builtin_amdgcn_s_setprio(1);
        #pragma unroll
        for (int fp = 0; fp < 16; ++fp) {
            const long* ap = (const long*)&buf[fp * 1024 + lane * 16];
            long a0 = ap[0], a1 = ap[1];
            CA = __builtin_amdgcn_mfma_f32_32x32x16_fp8_fp8(a0, qq[2 * fp], CA, 0, 0, 0);
            CB = __builtin_amdgcn_mfma_f32_32x32x16_fp8_fp8(a1, qq[2 * fp + 1], CB, 0, 0, 0);
            if (fp == 9)  ldV(T);
            if (fp == 10) ldCB(T);
        }
        __builtin_amdgcn_s_setprio(0);
    };
    auto sm_pv = [&](const f32x16& PA, const f32x16& PB) {
        float pex[16];
        float lsA = 0.f, lsB = 0.f;
        #pragma unroll
        for (int R = 0; R < 16; R += 2) {
            float x0 = fmaf(PA[R] + PB[R], SC, cbfv(R));
            float x1 = fmaf(PA[R + 1] + PB[R + 1], SC, cbfv(R + 1));
            float e0, e1;
            asm("v_exp_f32 %0, %1" : "=v"(e0) : "v"(x0));
            asm("v_exp_f32 %0, %1" : "=v"(e1) : "v"(x1));
            pex[R] = e0; pex[R + 1] = e1;
            lsA += e0; lsB += e1;
        }
        lsum += lsA + lsB;
        pack_pv(pex);
    };
    auto zero16 = [](f32x16& v) {
        #pragma unroll
        for (int i = 0; i < 16; ++i) v[i] = 0.f;
    };

    // ---- prologue: 2 K-tiles in flight ----
    stageK2(0, 0); stageK2(1, 1);

    // ---- phase 0 (bank0, buf0) ----
    zero16(aA0); zero16(aB0);
    asm volatile("s_waitcnt vmcnt(4)" ::: "memory");
    __builtin_amdgcn_s_barrier();
    tile_plain(&sK[0][0], 0, aA0, aB0);
    stageK2(2, 2);

    // ---- phases 1..30 (ring: tile t -> buf t%3; stage t+2 -> buf (t+2)%3) ----
    int cur = 1;
    for (int t = 1; t <= 30; t += 2) {
        zero16(aA1); zero16(aB1);
        asm volatile("s_waitcnt vmcnt(4)" ::: "memory");
        __builtin_amdgcn_s_barrier();
        tile_fused(&sK[cur][0], t, aA1, aB1, aA0, aB0);
        if (t + 2 <= 31) stageK2(t + 2, (cur + 2 >= 3) ? cur - 1 : cur + 2);
        cur = (cur == 2) ? 0 : cur + 1;

        zero16(aA0); zero16(aB0);
        asm volatile("s_waitcnt vmcnt(4)" ::: "memory");
        __builtin_amdgcn_s_barrier();
        tile_fused(&sK[cur][0], t + 1, aA0, aB0, aA1, aB1);
        if (t + 3 <= 31) stageK2(t + 3, (cur + 2 >= 3) ? cur - 1 : cur + 2);
        cur = (cur == 2) ? 0 : cur + 1;
    }

    // ---- phase 31 (bank1, buf cur=1; deferred softmax of 30 in bank0) ----
    {
        zero16(aA1); zero16(aB1);
        asm volatile("s_waitcnt vmcnt(0)" ::: "memory");
        __builtin_amdgcn_s_barrier();
        tile_fused(&sK[cur][0], 31, aA1, aB1, aA0, aB0);
        asm volatile("s_waitcnt vmcnt(0)" ::: "memory");
        sm_pv(aA1, aB1);
    }

    // ---- epilogue: lsum; O^T -> q-major via sO = sK[0] (free: tile30 was the last buf0 reader,
    // and every wave passed the phase-31 barrier after it) — NO extra barrier; b64-packed writes;
    // intra-wave LDS RAW only (wave w owns rows [32w,32w+32) for both write and dump) ----
    lsum += __shfl_xor(lsum, 32);
    if (hi == 0) lpart[(size_t)bid * 128 + w * 32 + l31] = lsum;
    {
        _Float16* sO = (_Float16*)&sK[0][0];           // [128][72] halves (stride 144 B)
        const int q = w * 32 + l31;
        #pragma unroll
        for (int u = 0; u < 4; ++u) {
            half4 v0, v1;
            v0[0] = (_Float16)acco0[4 * u];     v0[1] = (_Float16)acco0[4 * u + 1];
            v0[2] = (_Float16)acco0[4 * u + 2]; v0[3] = (_Float16)acco0[4 * u + 3];
            v1[0] = (_Float16)acco1[4 * u];     v1[1] = (_Float16)acco1[4 * u + 1];
            v1[2] = (_Float16)acco1[4 * u + 2]; v1[3] = (_Float16)acco1[4 * u + 3];
            *(half4*)&sO[q * 72 + u * 8 + 4 * hi]      = v0;   // dh = 8u + 4hi + 0..3
            *(half4*)&sO[q * 72 + 32 + u * 8 + 4 * hi] = v1;
        }
        const int qd = tid >> 1, hf = tid & 1;
        _Float16* dst = Opart + ((size_t)bid << 13) + qd * 64 + hf * 32;
        const _Float16* srcp = sO + qd * 72 + hf * 32;
        #pragma unroll
        for (int k = 0; k < 4; ++k)
            *(half8*)(dst + k * 8) = *(const half8*)(srcp + k * 8);
    }
}

extern "C" void kernel_launch(void* const* d_in, const int* in_sizes, int n_in,
                              void* d_out, int out_size, void* d_ws, size_t ws_size,
                              hipStream_t stream) {
    (void)in_sizes; (void)n_in; (void)out_size; (void)ws_size;
    const float* x      = (const float*)d_in[0];
    const float* Wq     = (const float*)d_in[1];
    const float* Wk     = (const float*)d_in[2];
    const float* Wv     = (const float*)d_in[3];
    const float* Wb     = (const float*)d_in[4];
    const float* mixing = (const float*)d_in[5];
    const float* Wd     = (const float*)d_in[6];
    const float* bd     = (const float*)d_in[7];
    float* out = (float*)d_out;

    char* ws = (char*)d_ws;
    const size_t MiB = 1048576;
    unsigned short* xb     = (unsigned short*)(ws);                  // [0,4) MiB
    unsigned short* qb     = (unsigned short*)(ws + 4 * MiB);        // [4,8) bf16 q row-major
    unsigned char*  kpack8 = (unsigned char*)(ws + 8 * MiB);         // [8,10) fp8 K A-frags (x32)
    unsigned short* vfrag  = (unsigned short*)(ws + 10 * MiB);       // [10,14)
    unsigned short* Wqb    = (unsigned short*)(ws + 18 * MiB);
    unsigned short* Wkb    = (unsigned short*)(ws + 18 * MiB + 512 * 1024);
    unsigned short* Wvb    = (unsigned short*)(ws + 19 * MiB);
    unsigned short* Wdb    = (unsigned short*)(ws + 19 * MiB + 512 * 1024);
    float* cbuf            = (float*)(ws + 20 * MiB);                // 128 KB (f32 frag-major)
    float* lpart           = (float*)(ws + 20 * MiB + 256 * 1024);   // 256 KB
    _Float16* Opart        = (_Float16*)(ws + 21 * MiB);             // [21,29) 8 MB, q-major

    cvt_cb<<<4096, 256, 0, stream>>>(x, Wq, Wk, Wv, Wd, Wb, xb, Wqb, Wkb, Wvb, Wdb, cbuf);
    gemm_qkv<<<dim3(32, 4, 3), 256, 0, stream>>>(xb, Wqb, Wkb, Wvb, qb, kpack8, vfrag);
    flash_attn<<<512, 256, 0, stream>>>(qb, kpack8, vfrag, cbuf, mixing, Opart, lpart);
    gemm_out<<<dim3(32, 4), 256, 0, stream>>>(Opart, lpart, Wdb, bd, out);
}